// Round 7
// baseline (349.861 us; speedup 1.0000x reference)
//
#include <hip/hip_runtime.h>
#include <math.h>

#define D     64
#define NSLOT 8
#define NB    64
#define NROW  4096
#define EPS   1e-5f
#define LOG2E 1.44269504f
#define SCK   (0.125f * LOG2E)   // 1/sqrt(64) * 1/ln2, folded into q~ and c

// ---------------------------------------------------------------------------
// helpers
// ---------------------------------------------------------------------------
__device__ __forceinline__ float wredsum(float v) {
  #pragma unroll
  for (int m = 1; m < 64; m <<= 1) v += __shfl_xor(v, m);
  return v;
}

// Coalesced wave matvec, full register preload: out[r] = W[r,:].lin, C=64.
template <int R>
__device__ __forceinline__ void matvec_pre(const float* __restrict__ W,
                                           const float* lin, float* lout,
                                           int lane) {
  const int g = lane >> 4, q = lane & 15;
  float4 w[R >> 2];
  #pragma unroll
  for (int rb = 0; rb < (R >> 2); ++rb)
    w[rb] = *reinterpret_cast<const float4*>(W + (rb * 4 + g) * 64 + 4 * q);
  const float4 iv = *reinterpret_cast<const float4*>(lin + 4 * q);
  #pragma unroll
  for (int rb = 0; rb < (R >> 2); ++rb) {
    float p = w[rb].x * iv.x + w[rb].y * iv.y + w[rb].z * iv.z + w[rb].w * iv.w;
    p += __shfl_xor(p, 1);
    p += __shfl_xor(p, 2);
    p += __shfl_xor(p, 4);
    p += __shfl_xor(p, 8);
    if (q == 0) lout[rb * 4 + g] = p;
  }
}

// Same, C=128.
template <int R>
__device__ __forceinline__ void matvec_pre_c128(const float* __restrict__ W,
                                                const float* lin, float* lout,
                                                int lane) {
  const int g = lane >> 4, q = lane & 15;
  float4 w0[R >> 2], w1[R >> 2];
  #pragma unroll
  for (int rb = 0; rb < (R >> 2); ++rb) {
    w0[rb] = *reinterpret_cast<const float4*>(W + (rb * 4 + g) * 128 + 4 * q);
    w1[rb] = *reinterpret_cast<const float4*>(W + (rb * 4 + g) * 128 + 64 + 4 * q);
  }
  const float4 iv0 = *reinterpret_cast<const float4*>(lin + 4 * q);
  const float4 iv1 = *reinterpret_cast<const float4*>(lin + 64 + 4 * q);
  #pragma unroll
  for (int rb = 0; rb < (R >> 2); ++rb) {
    float p = w0[rb].x * iv0.x + w0[rb].y * iv0.y + w0[rb].z * iv0.z + w0[rb].w * iv0.w
            + w1[rb].x * iv1.x + w1[rb].y * iv1.y + w1[rb].z * iv1.z + w1[rb].w * iv1.w;
    p += __shfl_xor(p, 1);
    p += __shfl_xor(p, 2);
    p += __shfl_xor(p, 4);
    p += __shfl_xor(p, 8);
    if (q == 0) lout[rb * 4 + g] = p;
  }
}

// ---------------------------------------------------------------------------
// KA: big pass over x. 2048 blocks x 256 thr (8 waves/SIMD when resident).
// Per 16-lane group/row: LN, logits vs 8 slots (distributed-owner reduce:
// lane (l>>1)&7 owns one slot), cross-lane softmax, shuffle broadcast,
// rank-8 accumulate. q~ staged in LDS (frees VGPRs; target <=64 for 8 waves).
// q~/c arrive pre-scaled by 1/ln2 -> exp2 direct.
// ---------------------------------------------------------------------------
__global__ __launch_bounds__(256, 8)
void ka_kernel(const float* __restrict__ x,
               const float* __restrict__ qtil,
               const float* __restrict__ cvec,
               float* __restrict__ U, float* __restrict__ S) {
  const int b    = blockIdx.x >> 5;   // 32 row-blocks per batch
  const int rb   = blockIdx.x & 31;
  const int tid  = threadIdx.x;
  const int wave = tid >> 6;
  const int lane = tid & 63;
  const int c    = lane & 15;         // d-chunk (4 floats)
  const int sown = (lane >> 1) & 7;   // slot owned in distributed reduce

  __shared__ float qs[NSLOT * D];
  __shared__ float lU[4][NSLOT][D];
  __shared__ float lS[4][NSLOT];

  if (tid < 128)
    reinterpret_cast<float4*>(qs)[tid] =
        reinterpret_cast<const float4*>(qtil + (size_t)b * NSLOT * D)[tid];
  const float cs_own = cvec[b * NSLOT + sown];
  __syncthreads();

  const float4* qs4 = reinterpret_cast<const float4*>(qs);

  float4 Ua[NSLOT];
  #pragma unroll
  for (int s = 0; s < NSLOT; ++s) Ua[s] = make_float4(0.f, 0.f, 0.f, 0.f);
  float Sa = 0.f;

  const float4* xb = reinterpret_cast<const float4*>(
      x + ((size_t)b * NROW + rb * 128 + wave * 32) * D);

  #pragma unroll 1
  for (int it = 0; it < 8; ++it) {
    float4 xv = xb[it * 64 + lane];

    // LayerNorm over 16-lane group
    float s1 = xv.x + xv.y + xv.z + xv.w;
    float s2 = xv.x * xv.x + xv.y * xv.y + xv.z * xv.z + xv.w * xv.w;
    #pragma unroll
    for (int m = 1; m < 16; m <<= 1) {
      s1 += __shfl_xor(s1, m);
      s2 += __shfl_xor(s2, m);
    }
    float mean = s1 * (1.f / 64.f);
    float var  = s2 * (1.f / 64.f) - mean * mean;
    float rstd = rsqrtf(var + EPS);
    float nb   = -mean * rstd;
    float4 xn;
    xn.x = fmaf(xv.x, rstd, nb);
    xn.y = fmaf(xv.y, rstd, nb);
    xn.z = fmaf(xv.z, rstd, nb);
    xn.w = fmaf(xv.w, rstd, nb);

    // partial dots (lane's 4 d's, all 8 slots; q~ from LDS broadcast)
    float p[NSLOT];
    #pragma unroll
    for (int s = 0; s < NSLOT; ++s) {
      float4 qv = qs4[s * 16 + c];
      p[s] = xn.x * qv.x + xn.y * qv.y + xn.z * qv.z + xn.w * qv.w;
    }

    // distributed butterfly: lane ends owning slot sown's full group-sum
    const bool h3 = (lane & 8) != 0;
    float t0 = __shfl_xor(p[0], 8), t1 = __shfl_xor(p[1], 8);
    float t2 = __shfl_xor(p[2], 8), t3 = __shfl_xor(p[3], 8);
    float t4 = __shfl_xor(p[4], 8), t5 = __shfl_xor(p[5], 8);
    float t6 = __shfl_xor(p[6], 8), t7 = __shfl_xor(p[7], 8);
    float r0 = (h3 ? p[4] : p[0]) + (h3 ? t4 : t0);
    float r1 = (h3 ? p[5] : p[1]) + (h3 ? t5 : t1);
    float r2 = (h3 ? p[6] : p[2]) + (h3 ? t6 : t2);
    float r3 = (h3 ? p[7] : p[3]) + (h3 ? t7 : t3);
    const bool h2 = (lane & 4) != 0;
    float u0 = __shfl_xor(r0, 4), u1 = __shfl_xor(r1, 4);
    float u2 = __shfl_xor(r2, 4), u3 = __shfl_xor(r3, 4);
    float v0 = (h2 ? r2 : r0) + (h2 ? u2 : u0);
    float v1 = (h2 ? r3 : r1) + (h2 ? u3 : u1);
    const bool h1 = (lane & 2) != 0;
    float w0 = __shfl_xor(v0, 2), w1 = __shfl_xor(v1, 2);
    float z  = (h1 ? v1 : v0) + (h1 ? w1 : w0);
    z += __shfl_xor(z, 1);

    // softmax across slot-owner lanes (log2 domain; q~/c pre-scaled)
    float logit = z + cs_own;
    float mx = logit;
    mx = fmaxf(mx, __shfl_xor(mx, 2));
    mx = fmaxf(mx, __shfl_xor(mx, 4));
    mx = fmaxf(mx, __shfl_xor(mx, 8));
    float e = exp2f(logit - mx);
    float sum = e;
    sum += __shfl_xor(sum, 2);
    sum += __shfl_xor(sum, 4);
    sum += __shfl_xor(sum, 8);
    float a_own = e * (1.f / sum) + 1e-8f;
    Sa += a_own;

    // broadcast a[s] to the whole group, accumulate rank-8 outer product
    const int gb = lane & 48;
    #pragma unroll
    for (int s = 0; s < NSLOT; ++s) {
      float as = __shfl(a_own, gb + 2 * s);
      Ua[s].x = fmaf(as, xn.x, Ua[s].x);
      Ua[s].y = fmaf(as, xn.y, Ua[s].y);
      Ua[s].z = fmaf(as, xn.z, Ua[s].z);
      Ua[s].w = fmaf(as, xn.w, Ua[s].w);
    }
  }

  // cross-group reduce (masks 16,32)
  #pragma unroll
  for (int m = 16; m < 64; m <<= 1) {
    Sa += __shfl_xor(Sa, m);
    #pragma unroll
    for (int s = 0; s < NSLOT; ++s) {
      Ua[s].x += __shfl_xor(Ua[s].x, m);
      Ua[s].y += __shfl_xor(Ua[s].y, m);
      Ua[s].z += __shfl_xor(Ua[s].z, m);
      Ua[s].w += __shfl_xor(Ua[s].w, m);
    }
  }

  if (lane < 16) {
    #pragma unroll
    for (int s = 0; s < NSLOT; ++s) {
      lU[wave][s][4 * c + 0] = Ua[s].x;
      lU[wave][s][4 * c + 1] = Ua[s].y;
      lU[wave][s][4 * c + 2] = Ua[s].z;
      lU[wave][s][4 * c + 3] = Ua[s].w;
    }
    if ((lane & 1) == 0) lS[wave][lane >> 1] = Sa;
  }
  __syncthreads();

  for (int cell = tid; cell < NSLOT * D; cell += 256) {
    int s = cell >> 6, d = cell & 63;
    atomicAdd(&U[((size_t)b * NSLOT + s) * D + d],
              lU[0][s][d] + lU[1][s][d] + lU[2][s][d] + lU[3][s][d]);
  }
  if (tid < NSLOT) {
    atomicAdd(&S[b * NSLOT + tid],
              lS[0][tid] + lS[1][tid] + lS[2][tid] + lS[3][tid]);
  }
}

// ---------------------------------------------------------------------------
// prep work (4 blocks of 128 thr, appended to the mode-0 kb launch):
//  pb0: Mt[d][e] = sum_f Wq[f][e]*Wk[f][d]; ct[d]=sum bq*Wk[:,d];
//       u[e]=sum bk*Wq[:,e]; c0 = bk.bq
//  pb1-3: G = Wih @ Wv (192x64); bias_i = Wih @ bv + bih
// ---------------------------------------------------------------------------
__device__ void prep_block(int pb,
                           const float* __restrict__ Wq, const float* __restrict__ bq,
                           const float* __restrict__ Wk, const float* __restrict__ bk,
                           const float* __restrict__ Wv, const float* __restrict__ bv,
                           const float* __restrict__ Wih, const float* __restrict__ bih,
                           float* __restrict__ Mt, float* __restrict__ ct,
                           float* __restrict__ u, float* __restrict__ c0,
                           float* __restrict__ G, float* __restrict__ bias_i) {
  const int t = threadIdx.x;  // 0..127
  float acc[32];
  #pragma unroll
  for (int j = 0; j < 32; ++j) acc[j] = 0.f;
  if (pb == 0) {
    const int row = t >> 1;
    const int cb  = (t & 1) * 32;
    for (int f = 0; f < 64; ++f) {
      float wkf = Wk[f * 64 + row];
      const float4* wq4 = reinterpret_cast<const float4*>(Wq + f * 64 + cb);
      #pragma unroll
      for (int j4 = 0; j4 < 8; ++j4) {
        float4 wq = wq4[j4];
        acc[4 * j4 + 0] = fmaf(wkf, wq.x, acc[4 * j4 + 0]);
        acc[4 * j4 + 1] = fmaf(wkf, wq.y, acc[4 * j4 + 1]);
        acc[4 * j4 + 2] = fmaf(wkf, wq.z, acc[4 * j4 + 2]);
        acc[4 * j4 + 3] = fmaf(wkf, wq.w, acc[4 * j4 + 3]);
      }
    }
    #pragma unroll
    for (int j = 0; j < 32; ++j) Mt[row * 64 + cb + j] = acc[j];
    if (t < 64) {
      float a = 0.f, bsum = 0.f;
      for (int f = 0; f < 64; ++f) {
        a    = fmaf(bq[f], Wk[f * 64 + t], a);
        bsum = fmaf(bk[f], Wq[f * 64 + t], bsum);
      }
      ct[t] = a;
      u[t]  = bsum;
    }
    if (t == 0) {
      float a = 0.f;
      for (int f = 0; f < 64; ++f) a = fmaf(bk[f], bq[f], a);
      c0[0] = a;
    }
  } else {
    const int r0  = (pb - 1) * 64;
    const int row = r0 + (t >> 1);
    const int cb  = (t & 1) * 32;
    for (int f = 0; f < 64; ++f) {
      float wih = Wih[row * 64 + f];
      const float4* wv4 = reinterpret_cast<const float4*>(Wv + f * 64 + cb);
      #pragma unroll
      for (int j4 = 0; j4 < 8; ++j4) {
        float4 wv = wv4[j4];
        acc[4 * j4 + 0] = fmaf(wih, wv.x, acc[4 * j4 + 0]);
        acc[4 * j4 + 1] = fmaf(wih, wv.y, acc[4 * j4 + 1]);
        acc[4 * j4 + 2] = fmaf(wih, wv.z, acc[4 * j4 + 2]);
        acc[4 * j4 + 3] = fmaf(wih, wv.w, acc[4 * j4 + 3]);
      }
    }
    #pragma unroll
    for (int j = 0; j < 32; ++j) G[row * 64 + cb + j] = acc[j];
    if (t < 64) {
      int rr = r0 + t;
      float a = bih[rr];
      for (int f = 0; f < 64; ++f) a = fmaf(Wih[rr * 64 + f], bv[f], a);
      bias_i[rr] = a;
    }
  }
}

// ---------------------------------------------------------------------------
// KB: per-(batch,slot), 128 threads = 2 waves. mode0: init slots + q~ via
// unfolded path (no prep dependency; prep blocks ride along in this launch).
// mode1: wave0 gi=G@ub, wave1 gh=Whh@h concurrently; GRU+LN on wave0;
// W1/W2/Mt split across both waves. q~/c written pre-scaled by 1/ln2.
// Folded tensors passed as writable pointers (prep path writes them;
// compute path only reads).
// ---------------------------------------------------------------------------
__global__ __launch_bounds__(128, 1)
void kb_kernel(int mode, int last,
               const float* __restrict__ noise, const float* __restrict__ mu,
               const float* __restrict__ sigma,
               const float* __restrict__ Wq, const float* __restrict__ bq,
               const float* __restrict__ Wk, const float* __restrict__ bk,
               const float* __restrict__ Wv, const float* __restrict__ bv,
               const float* __restrict__ Wih, const float* __restrict__ bih,
               float* __restrict__ G, float* __restrict__ bias_i,
               const float* __restrict__ Whh, const float* __restrict__ bhh,
               const float* __restrict__ W1, const float* __restrict__ b1,
               const float* __restrict__ W2, const float* __restrict__ b2,
               float* __restrict__ Mt, float* __restrict__ ct,
               float* __restrict__ u, float* __restrict__ c0,
               float* __restrict__ slots, float* __restrict__ qtil,
               float* __restrict__ cvec, float* __restrict__ U,
               float* __restrict__ S, float* __restrict__ out) {
  if (blockIdx.x >= NB * NSLOT) {  // prep blocks (mode-0 launch only)
    prep_block(blockIdx.x - NB * NSLOT, Wq, bq, Wk, bk, Wv, bv, Wih, bih,
               Mt, ct, u, c0, G, bias_i);
    return;
  }

  const int blk = blockIdx.x;
  const int b   = blk >> 3;
  const int s   = blk & 7;
  const int wv  = threadIdx.x >> 6;
  const int d   = threadIdx.x & 63;
  const int idx = (b * NSLOT + s) * D + d;

  __shared__ float bufA[64];
  __shared__ float bufQ[64];
  __shared__ float gi[192];
  __shared__ float gh[192];
  __shared__ float bufH[128];

  if (mode == 0) {
    if (wv == 0) {
      float h = mu[d] + sigma[d] * noise[idx];
      slots[idx] = h;
      U[idx] = 0.f;
      if (d == 0) S[b * NSLOT + s] = 0.f;
      // q~ unfolded: ln=LN(h); q=Wq@ln+bq; qt=q@Wk; c=bk.q (wave-local)
      float m  = wredsum(h) * (1.f / 64.f);
      float hc = h - m;
      float v  = wredsum(hc * hc) * (1.f / 64.f);
      float ln = hc * rsqrtf(v + EPS);
      bufA[d] = ln;
      matvec_pre<64>(Wq, bufA, gi, d);
      float qv = gi[d] + bq[d];
      bufQ[d] = qv;
      float qt0 = 0.f, qt1 = 0.f, qt2 = 0.f, qt3 = 0.f;
      #pragma unroll
      for (int e = 0; e < 64; e += 4) {
        const float4 qb = *reinterpret_cast<const float4*>(bufQ + e);
        qt0 = fmaf(Wk[(e + 0) * D + d], qb.x, qt0);
        qt1 = fmaf(Wk[(e + 1) * D + d], qb.y, qt1);
        qt2 = fmaf(Wk[(e + 2) * D + d], qb.z, qt2);
        qt3 = fmaf(Wk[(e + 3) * D + d], qb.w, qt3);
      }
      qtil[idx] = ((qt0 + qt1) + (qt2 + qt3)) * SCK;
      float ca = wredsum(bk[d] * qv) * SCK;
      if (d == 0) cvec[b * NSLOT + s] = ca;
    }
    return;
  }

  // ---- mode 1 ----
  float h = 0.f, sl = 0.f;
  if (wv == 0) {
    float Uv = U[idx];
    float Ss = S[b * NSLOT + s];
    U[idx] = 0.f;
    if (d == 0) S[b * NSLOT + s] = 0.f;
    bufA[d] = Uv / Ss;
    h = slots[idx];
    bufH[d] = h;
  }
  __syncthreads();
  if (wv == 0) matvec_pre<192>(G,   bufA, gi, d);
  else         matvec_pre<192>(Whh, bufH, gh, d);
  __syncthreads();
  if (wv == 0) {
    float r  = 1.f / (1.f + expf(-(gi[d]        + bias_i[d]        + gh[d]        + bhh[d])));
    float z  = 1.f / (1.f + expf(-(gi[64 + d]   + bias_i[64 + d]   + gh[64 + d]   + bhh[64 + d])));
    float nn = tanhf(gi[128 + d] + bias_i[128 + d] + r * (gh[128 + d] + bhh[128 + d]));
    h = (1.f - z) * nn + z * h;
    float m  = wredsum(h) * (1.f / 64.f);
    float hc = h - m;
    float v  = wredsum(hc * hc) * (1.f / 64.f);
    sl = hc * rsqrtf(v + EPS);
    bufA[d] = sl;
  }
  __syncthreads();
  matvec_pre<64>(W1 + wv * 64 * 64, bufA, gi + wv * 64, d);
  __syncthreads();
  bufH[threadIdx.x] = fmaxf(gi[threadIdx.x] + b1[threadIdx.x], 0.f);
  __syncthreads();
  matvec_pre_c128<32>(W2 + wv * 32 * 128, bufH, gh + wv * 32, d);
  __syncthreads();
  if (wv == 0) {
    h = sl + gh[d] + b2[d];
    slots[idx] = h;
    if (last) out[idx] = h;
  }

  if (!last) {
    if (wv == 0) {
      float m  = wredsum(h) * (1.f / 64.f);
      float hc = h - m;
      float v  = wredsum(hc * hc) * (1.f / 64.f);
      float ln = hc * rsqrtf(v + EPS);
      bufA[d] = ln;
    }
    __syncthreads();
    matvec_pre<32>(Mt + wv * 32 * 64, bufA, gi + wv * 32, d);
    __syncthreads();
    if (wv == 0) {
      qtil[idx] = SCK * (gi[d] + ct[d]);
      float ca = (wredsum(u[d] * bufA[d]) + c0[0]) * SCK;
      if (d == 0) cvec[b * NSLOT + s] = ca;
    }
  }
}

// ---------------------------------------------------------------------------
extern "C" void kernel_launch(void* const* d_in, const int* in_sizes, int n_in,
                              void* d_out, int out_size, void* d_ws, size_t ws_size,
                              hipStream_t stream) {
  (void)in_sizes; (void)n_in; (void)out_size; (void)ws_size;
  const float* x     = (const float*)d_in[0];
  const float* noise = (const float*)d_in[1];
  const float* Wq    = (const float*)d_in[2];
  const float* bq    = (const float*)d_in[3];
  const float* Wk    = (const float*)d_in[4];
  const float* bk    = (const float*)d_in[5];
  const float* Wv    = (const float*)d_in[6];
  const float* bv    = (const float*)d_in[7];
  const float* Wih   = (const float*)d_in[8];
  const float* Whh   = (const float*)d_in[9];
  const float* bih   = (const float*)d_in[10];
  const float* bhh   = (const float*)d_in[11];
  const float* W1    = (const float*)d_in[12];
  const float* b1    = (const float*)d_in[13];
  const float* W2    = (const float*)d_in[14];
  const float* b2    = (const float*)d_in[15];
  const float* mu    = (const float*)d_in[16];
  const float* sigma = (const float*)d_in[17];

  float* ws     = (float*)d_ws;
  float* slots  = ws;           // 32768
  float* qtil   = ws + 32768;   // 32768
  float* cvec   = ws + 65536;   // 512
  float* U      = ws + 66048;   // 32768
  float* S      = ws + 98816;   // 512
  float* Mt     = ws + 99328;   // 4096
  float* ct     = ws + 103424;  // 64
  float* uvec   = ws + 103488;  // 64
  float* c0     = ws + 103552;  // 4 (padded)
  float* G      = ws + 103556;  // 12288
  float* bias_i = ws + 115844;  // 192
  float* out    = (float*)d_out;

  auto launch_kb = [&](int mode, int last, int nblk) {
    kb_kernel<<<nblk, 128, 0, stream>>>(mode, last, noise, mu, sigma,
                                        Wq, bq, Wk, bk, Wv, bv, Wih, bih,
                                        G, bias_i, Whh, bhh, W1, b1, W2, b2,
                                        Mt, ct, uvec, c0,
                                        slots, qtil, cvec, U, S, out);
  };

  launch_kb(0, 0, NB * NSLOT + 4);  // init + q~ (unfolded) + prep blocks
  for (int it = 1; it <= 3; ++it) {
    ka_kernel<<<NB * 32, 256, 0, stream>>>(x, qtil, cvec, U, S);
    launch_kb(1, it == 3 ? 1 : 0, NB * NSLOT);
  }
}

// Round 8
// 218.192 us; speedup vs baseline: 1.6035x; 1.6035x over previous
//
#include <hip/hip_runtime.h>
#include <math.h>

#define D     64
#define NSLOT 8
#define NB    64
#define NROW  4096
#define EPS   1e-5f
#define LOG2E 1.44269504f
#define SCK   (0.125f * LOG2E)   // 1/sqrt(64) * 1/ln2, folded into q~ and c

// ---------------------------------------------------------------------------
// helpers
// ---------------------------------------------------------------------------
__device__ __forceinline__ float wredsum(float v) {
  #pragma unroll
  for (int m = 1; m < 64; m <<= 1) v += __shfl_xor(v, m);
  return v;
}

// Coalesced wave matvec, full register preload: out[r] = W[r,:].lin, C=64.
template <int R>
__device__ __forceinline__ void matvec_pre(const float* __restrict__ W,
                                           const float* lin, float* lout,
                                           int lane) {
  const int g = lane >> 4, q = lane & 15;
  float4 w[R >> 2];
  #pragma unroll
  for (int rb = 0; rb < (R >> 2); ++rb)
    w[rb] = *reinterpret_cast<const float4*>(W + (rb * 4 + g) * 64 + 4 * q);
  const float4 iv = *reinterpret_cast<const float4*>(lin + 4 * q);
  #pragma unroll
  for (int rb = 0; rb < (R >> 2); ++rb) {
    float p = w[rb].x * iv.x + w[rb].y * iv.y + w[rb].z * iv.z + w[rb].w * iv.w;
    p += __shfl_xor(p, 1);
    p += __shfl_xor(p, 2);
    p += __shfl_xor(p, 4);
    p += __shfl_xor(p, 8);
    if (q == 0) lout[rb * 4 + g] = p;
  }
}

// Same, C=128.
template <int R>
__device__ __forceinline__ void matvec_pre_c128(const float* __restrict__ W,
                                                const float* lin, float* lout,
                                                int lane) {
  const int g = lane >> 4, q = lane & 15;
  float4 w0[R >> 2], w1[R >> 2];
  #pragma unroll
  for (int rb = 0; rb < (R >> 2); ++rb) {
    w0[rb] = *reinterpret_cast<const float4*>(W + (rb * 4 + g) * 128 + 4 * q);
    w1[rb] = *reinterpret_cast<const float4*>(W + (rb * 4 + g) * 128 + 64 + 4 * q);
  }
  const float4 iv0 = *reinterpret_cast<const float4*>(lin + 4 * q);
  const float4 iv1 = *reinterpret_cast<const float4*>(lin + 64 + 4 * q);
  #pragma unroll
  for (int rb = 0; rb < (R >> 2); ++rb) {
    float p = w0[rb].x * iv0.x + w0[rb].y * iv0.y + w0[rb].z * iv0.z + w0[rb].w * iv0.w
            + w1[rb].x * iv1.x + w1[rb].y * iv1.y + w1[rb].z * iv1.z + w1[rb].w * iv1.w;
    p += __shfl_xor(p, 1);
    p += __shfl_xor(p, 2);
    p += __shfl_xor(p, 4);
    p += __shfl_xor(p, 8);
    if (q == 0) lout[rb * 4 + g] = p;
  }
}

// ---------------------------------------------------------------------------
// KA: big pass over x — round-5 body (60 VGPR, no spill), grid doubled to
// 2048 blocks (32 row-blocks x 128 rows) so the grid supplies 8 waves/SIMD.
// NOTE: q~/c now arrive pre-scaled by 1/ln2 (SCK) -> exp2f without rescale.
// ---------------------------------------------------------------------------
__global__ __launch_bounds__(256, 2)
void ka_kernel(const float* __restrict__ x,
               const float* __restrict__ qtil,
               const float* __restrict__ cvec,
               float* __restrict__ U, float* __restrict__ S) {
  const int b    = blockIdx.x >> 5;   // 32 row-blocks per batch
  const int rb   = blockIdx.x & 31;
  const int tid  = threadIdx.x;
  const int wave = tid >> 6;
  const int lane = tid & 63;
  const int c    = lane & 15;         // d-chunk index (4 floats)

  const float4* qt4 = reinterpret_cast<const float4*>(qtil + (size_t)b * NSLOT * D);
  float4 qf[NSLOT];
  float  cs[NSLOT];
  #pragma unroll
  for (int s = 0; s < NSLOT; ++s) {
    qf[s] = qt4[s * 16 + c];
    cs[s] = cvec[b * NSLOT + s];
  }

  float4 Ua[NSLOT];
  float  Sa[NSLOT];
  #pragma unroll
  for (int s = 0; s < NSLOT; ++s) { Ua[s] = make_float4(0.f, 0.f, 0.f, 0.f); Sa[s] = 0.f; }

  const float4* xb = reinterpret_cast<const float4*>(
      x + ((size_t)b * NROW + rb * 128 + wave * 32) * D);

  #pragma unroll 2
  for (int it = 0; it < 8; ++it) {
    float4 xv = xb[it * 64 + lane];  // 4 rows x 64 floats, fully coalesced

    // --- LayerNorm over the 16-lane group (row) ---
    float s1 = xv.x + xv.y + xv.z + xv.w;
    float s2 = xv.x * xv.x + xv.y * xv.y + xv.z * xv.z + xv.w * xv.w;
    #pragma unroll
    for (int m = 1; m < 16; m <<= 1) {
      s1 += __shfl_xor(s1, m);
      s2 += __shfl_xor(s2, m);
    }
    float mean = s1 * (1.f / 64.f);
    float var  = s2 * (1.f / 64.f) - mean * mean;
    float rstd = rsqrtf(var + EPS);
    float nb   = -mean * rstd;
    float4 xn;
    xn.x = fmaf(xv.x, rstd, nb);
    xn.y = fmaf(xv.y, rstd, nb);
    xn.z = fmaf(xv.z, rstd, nb);
    xn.w = fmaf(xv.w, rstd, nb);

    // --- logits (pre-scaled by 1/ln2) ---
    float p[NSLOT];
    #pragma unroll
    for (int s = 0; s < NSLOT; ++s)
      p[s] = xn.x * qf[s].x + xn.y * qf[s].y + xn.z * qf[s].z + xn.w * qf[s].w;
    #pragma unroll
    for (int m = 1; m < 16; m <<= 1) {
      #pragma unroll
      for (int s = 0; s < NSLOT; ++s) p[s] += __shfl_xor(p[s], m);
    }
    #pragma unroll
    for (int s = 0; s < NSLOT; ++s) p[s] += cs[s];

    // --- softmax over 8 slots (log2 domain; replicated in group) ---
    float mx = fmaxf(fmaxf(fmaxf(p[0], p[1]), fmaxf(p[2], p[3])),
                     fmaxf(fmaxf(p[4], p[5]), fmaxf(p[6], p[7])));
    float sum = 0.f;
    #pragma unroll
    for (int s = 0; s < NSLOT; ++s) {
      p[s] = exp2f(p[s] - mx);
      sum += p[s];
    }
    float inv = 1.f / sum;
    #pragma unroll
    for (int s = 0; s < NSLOT; ++s) {
      float a = p[s] * inv + 1e-8f;
      Sa[s] += a;
      Ua[s].x = fmaf(a, xn.x, Ua[s].x);
      Ua[s].y = fmaf(a, xn.y, Ua[s].y);
      Ua[s].z = fmaf(a, xn.z, Ua[s].z);
      Ua[s].w = fmaf(a, xn.w, Ua[s].w);
    }
  }

  // cross-group reduce within wave (masks 16, 32)
  #pragma unroll
  for (int m = 16; m < 64; m <<= 1) {
    #pragma unroll
    for (int s = 0; s < NSLOT; ++s) {
      Sa[s]   += __shfl_xor(Sa[s], m);
      Ua[s].x += __shfl_xor(Ua[s].x, m);
      Ua[s].y += __shfl_xor(Ua[s].y, m);
      Ua[s].z += __shfl_xor(Ua[s].z, m);
      Ua[s].w += __shfl_xor(Ua[s].w, m);
    }
  }

  __shared__ float lU[4][NSLOT][D];
  __shared__ float lS[4][NSLOT];
  if (lane < 16) {
    #pragma unroll
    for (int s = 0; s < NSLOT; ++s) {
      lU[wave][s][4 * c + 0] = Ua[s].x;
      lU[wave][s][4 * c + 1] = Ua[s].y;
      lU[wave][s][4 * c + 2] = Ua[s].z;
      lU[wave][s][4 * c + 3] = Ua[s].w;
    }
    if (c == 0) {
      #pragma unroll
      for (int s = 0; s < NSLOT; ++s) lS[wave][s] = Sa[s];
    }
  }
  __syncthreads();

  for (int cell = tid; cell < NSLOT * D; cell += 256) {
    int s = cell >> 6, d = cell & 63;
    atomicAdd(&U[((size_t)b * NSLOT + s) * D + d],
              lU[0][s][d] + lU[1][s][d] + lU[2][s][d] + lU[3][s][d]);
  }
  if (tid < NSLOT) {
    atomicAdd(&S[b * NSLOT + tid],
              lS[0][tid] + lS[1][tid] + lS[2][tid] + lS[3][tid]);
  }
}

// ---------------------------------------------------------------------------
// prep work (4 blocks of 128 thr, appended to the mode-0 kb launch):
//  pb0: Mt[d][e] = sum_f Wq[f][e]*Wk[f][d]; ct[d]=sum bq*Wk[:,d];
//       u[e]=sum bk*Wq[:,e]; c0 = bk.bq
//  pb1-3: G = Wih @ Wv (192x64); bias_i = Wih @ bv + bih
// ---------------------------------------------------------------------------
__device__ void prep_block(int pb,
                           const float* __restrict__ Wq, const float* __restrict__ bq,
                           const float* __restrict__ Wk, const float* __restrict__ bk,
                           const float* __restrict__ Wv, const float* __restrict__ bv,
                           const float* __restrict__ Wih, const float* __restrict__ bih,
                           float* __restrict__ Mt, float* __restrict__ ct,
                           float* __restrict__ u, float* __restrict__ c0,
                           float* __restrict__ G, float* __restrict__ bias_i) {
  const int t = threadIdx.x;  // 0..127
  float acc[32];
  #pragma unroll
  for (int j = 0; j < 32; ++j) acc[j] = 0.f;
  if (pb == 0) {
    const int row = t >> 1;
    const int cb  = (t & 1) * 32;
    for (int f = 0; f < 64; ++f) {
      float wkf = Wk[f * 64 + row];
      const float4* wq4 = reinterpret_cast<const float4*>(Wq + f * 64 + cb);
      #pragma unroll
      for (int j4 = 0; j4 < 8; ++j4) {
        float4 wq = wq4[j4];
        acc[4 * j4 + 0] = fmaf(wkf, wq.x, acc[4 * j4 + 0]);
        acc[4 * j4 + 1] = fmaf(wkf, wq.y, acc[4 * j4 + 1]);
        acc[4 * j4 + 2] = fmaf(wkf, wq.z, acc[4 * j4 + 2]);
        acc[4 * j4 + 3] = fmaf(wkf, wq.w, acc[4 * j4 + 3]);
      }
    }
    #pragma unroll
    for (int j = 0; j < 32; ++j) Mt[row * 64 + cb + j] = acc[j];
    if (t < 64) {
      float a = 0.f, bsum = 0.f;
      for (int f = 0; f < 64; ++f) {
        a    = fmaf(bq[f], Wk[f * 64 + t], a);
        bsum = fmaf(bk[f], Wq[f * 64 + t], bsum);
      }
      ct[t] = a;
      u[t]  = bsum;
    }
    if (t == 0) {
      float a = 0.f;
      for (int f = 0; f < 64; ++f) a = fmaf(bk[f], bq[f], a);
      c0[0] = a;
    }
  } else {
    const int r0  = (pb - 1) * 64;
    const int row = r0 + (t >> 1);
    const int cb  = (t & 1) * 32;
    for (int f = 0; f < 64; ++f) {
      float wih = Wih[row * 64 + f];
      const float4* wv4 = reinterpret_cast<const float4*>(Wv + f * 64 + cb);
      #pragma unroll
      for (int j4 = 0; j4 < 8; ++j4) {
        float4 wv = wv4[j4];
        acc[4 * j4 + 0] = fmaf(wih, wv.x, acc[4 * j4 + 0]);
        acc[4 * j4 + 1] = fmaf(wih, wv.y, acc[4 * j4 + 1]);
        acc[4 * j4 + 2] = fmaf(wih, wv.z, acc[4 * j4 + 2]);
        acc[4 * j4 + 3] = fmaf(wih, wv.w, acc[4 * j4 + 3]);
      }
    }
    #pragma unroll
    for (int j = 0; j < 32; ++j) G[row * 64 + cb + j] = acc[j];
    if (t < 64) {
      int rr = r0 + t;
      float a = bih[rr];
      for (int f = 0; f < 64; ++f) a = fmaf(Wih[rr * 64 + f], bv[f], a);
      bias_i[rr] = a;
    }
  }
}

// ---------------------------------------------------------------------------
// KB: per-(batch,slot), 128 threads = 2 waves (unchanged from round 7).
// ---------------------------------------------------------------------------
__global__ __launch_bounds__(128, 1)
void kb_kernel(int mode, int last,
               const float* __restrict__ noise, const float* __restrict__ mu,
               const float* __restrict__ sigma,
               const float* __restrict__ Wq, const float* __restrict__ bq,
               const float* __restrict__ Wk, const float* __restrict__ bk,
               const float* __restrict__ Wv, const float* __restrict__ bv,
               const float* __restrict__ Wih, const float* __restrict__ bih,
               float* __restrict__ G, float* __restrict__ bias_i,
               const float* __restrict__ Whh, const float* __restrict__ bhh,
               const float* __restrict__ W1, const float* __restrict__ b1,
               const float* __restrict__ W2, const float* __restrict__ b2,
               float* __restrict__ Mt, float* __restrict__ ct,
               float* __restrict__ u, float* __restrict__ c0,
               float* __restrict__ slots, float* __restrict__ qtil,
               float* __restrict__ cvec, float* __restrict__ U,
               float* __restrict__ S, float* __restrict__ out) {
  if (blockIdx.x >= NB * NSLOT) {  // prep blocks (mode-0 launch only)
    prep_block(blockIdx.x - NB * NSLOT, Wq, bq, Wk, bk, Wv, bv, Wih, bih,
               Mt, ct, u, c0, G, bias_i);
    return;
  }

  const int blk = blockIdx.x;
  const int b   = blk >> 3;
  const int s   = blk & 7;
  const int wv  = threadIdx.x >> 6;
  const int d   = threadIdx.x & 63;
  const int idx = (b * NSLOT + s) * D + d;

  __shared__ float bufA[64];
  __shared__ float bufQ[64];
  __shared__ float gi[192];
  __shared__ float gh[192];
  __shared__ float bufH[128];

  if (mode == 0) {
    if (wv == 0) {
      float h = mu[d] + sigma[d] * noise[idx];
      slots[idx] = h;
      U[idx] = 0.f;
      if (d == 0) S[b * NSLOT + s] = 0.f;
      // q~ unfolded: ln=LN(h); q=Wq@ln+bq; qt=q@Wk; c=bk.q (wave-local)
      float m  = wredsum(h) * (1.f / 64.f);
      float hc = h - m;
      float v  = wredsum(hc * hc) * (1.f / 64.f);
      float ln = hc * rsqrtf(v + EPS);
      bufA[d] = ln;
      matvec_pre<64>(Wq, bufA, gi, d);
      float qv = gi[d] + bq[d];
      bufQ[d] = qv;
      float qt0 = 0.f, qt1 = 0.f, qt2 = 0.f, qt3 = 0.f;
      #pragma unroll
      for (int e = 0; e < 64; e += 4) {
        const float4 qb = *reinterpret_cast<const float4*>(bufQ + e);
        qt0 = fmaf(Wk[(e + 0) * D + d], qb.x, qt0);
        qt1 = fmaf(Wk[(e + 1) * D + d], qb.y, qt1);
        qt2 = fmaf(Wk[(e + 2) * D + d], qb.z, qt2);
        qt3 = fmaf(Wk[(e + 3) * D + d], qb.w, qt3);
      }
      qtil[idx] = ((qt0 + qt1) + (qt2 + qt3)) * SCK;
      float ca = wredsum(bk[d] * qv) * SCK;
      if (d == 0) cvec[b * NSLOT + s] = ca;
    }
    return;
  }

  // ---- mode 1 ----
  float h = 0.f, sl = 0.f;
  if (wv == 0) {
    float Uv = U[idx];
    float Ss = S[b * NSLOT + s];
    U[idx] = 0.f;
    if (d == 0) S[b * NSLOT + s] = 0.f;
    bufA[d] = Uv / Ss;
    h = slots[idx];
    bufH[d] = h;
  }
  __syncthreads();
  if (wv == 0) matvec_pre<192>(G,   bufA, gi, d);
  else         matvec_pre<192>(Whh, bufH, gh, d);
  __syncthreads();
  if (wv == 0) {
    float r  = 1.f / (1.f + expf(-(gi[d]        + bias_i[d]        + gh[d]        + bhh[d])));
    float z  = 1.f / (1.f + expf(-(gi[64 + d]   + bias_i[64 + d]   + gh[64 + d]   + bhh[64 + d])));
    float nn = tanhf(gi[128 + d] + bias_i[128 + d] + r * (gh[128 + d] + bhh[128 + d]));
    h = (1.f - z) * nn + z * h;
    float m  = wredsum(h) * (1.f / 64.f);
    float hc = h - m;
    float v  = wredsum(hc * hc) * (1.f / 64.f);
    sl = hc * rsqrtf(v + EPS);
    bufA[d] = sl;
  }
  __syncthreads();
  matvec_pre<64>(W1 + wv * 64 * 64, bufA, gi + wv * 64, d);
  __syncthreads();
  bufH[threadIdx.x] = fmaxf(gi[threadIdx.x] + b1[threadIdx.x], 0.f);
  __syncthreads();
  matvec_pre_c128<32>(W2 + wv * 32 * 128, bufH, gh + wv * 32, d);
  __syncthreads();
  if (wv == 0) {
    h = sl + gh[d] + b2[d];
    slots[idx] = h;
    if (last) out[idx] = h;
  }

  if (!last) {
    if (wv == 0) {
      float m  = wredsum(h) * (1.f / 64.f);
      float hc = h - m;
      float v  = wredsum(hc * hc) * (1.f / 64.f);
      float ln = hc * rsqrtf(v + EPS);
      bufA[d] = ln;
    }
    __syncthreads();
    matvec_pre<32>(Mt + wv * 32 * 64, bufA, gi + wv * 32, d);
    __syncthreads();
    if (wv == 0) {
      qtil[idx] = SCK * (gi[d] + ct[d]);
      float ca = (wredsum(u[d] * bufA[d]) + c0[0]) * SCK;
      if (d == 0) cvec[b * NSLOT + s] = ca;
    }
  }
}

// ---------------------------------------------------------------------------
extern "C" void kernel_launch(void* const* d_in, const int* in_sizes, int n_in,
                              void* d_out, int out_size, void* d_ws, size_t ws_size,
                              hipStream_t stream) {
  (void)in_sizes; (void)n_in; (void)out_size; (void)ws_size;
  const float* x     = (const float*)d_in[0];
  const float* noise = (const float*)d_in[1];
  const float* Wq    = (const float*)d_in[2];
  const float* bq    = (const float*)d_in[3];
  const float* Wk    = (const float*)d_in[4];
  const float* bk    = (const float*)d_in[5];
  const float* Wv    = (const float*)d_in[6];
  const float* bv    = (const float*)d_in[7];
  const float* Wih   = (const float*)d_in[8];
  const float* Whh   = (const float*)d_in[9];
  const float* bih   = (const float*)d_in[10];
  const float* bhh   = (const float*)d_in[11];
  const float* W1    = (const float*)d_in[12];
  const float* b1    = (const float*)d_in[13];
  const float* W2    = (const float*)d_in[14];
  const float* b2    = (const float*)d_in[15];
  const float* mu    = (const float*)d_in[16];
  const float* sigma = (const float*)d_in[17];

  float* ws     = (float*)d_ws;
  float* slots  = ws;           // 32768
  float* qtil   = ws + 32768;   // 32768
  float* cvec   = ws + 65536;   // 512
  float* U      = ws + 66048;   // 32768
  float* S      = ws + 98816;   // 512
  float* Mt     = ws + 99328;   // 4096
  float* ct     = ws + 103424;  // 64
  float* uvec   = ws + 103488;  // 64
  float* c0     = ws + 103552;  // 4 (padded)
  float* G      = ws + 103556;  // 12288
  float* bias_i = ws + 115844;  // 192
  float* out    = (float*)d_out;

  auto launch_kb = [&](int mode, int last, int nblk) {
    kb_kernel<<<nblk, 128, 0, stream>>>(mode, last, noise, mu, sigma,
                                        Wq, bq, Wk, bk, Wv, bv, Wih, bih,
                                        G, bias_i, Whh, bhh, W1, b1, W2, b2,
                                        Mt, ct, uvec, c0,
                                        slots, qtil, cvec, U, S, out);
  };

  launch_kb(0, 0, NB * NSLOT + 4);  // init + q~ (unfolded) + prep blocks
  for (int it = 1; it <= 3; ++it) {
    ka_kernel<<<NB * 32, 256, 0, stream>>>(x, qtil, cvec, U, S);
    launch_kb(1, it == 3 ? 1 : 0, NB * NSLOT);
  }
}

// Round 9
// 200.519 us; speedup vs baseline: 1.7448x; 1.0881x over previous
//
#include <hip/hip_runtime.h>
#include <math.h>

#define D     64
#define NSLOT 8
#define NB    64
#define NROW  4096
#define NP    16          // row-blocks (partials) per batch
#define EPS   1e-5f
#define LOG2E 1.44269504f
#define SCK   (0.125f * LOG2E)   // 1/sqrt(64) * 1/ln2, folded into q~ and c

// ---------------------------------------------------------------------------
// helpers
// ---------------------------------------------------------------------------
__device__ __forceinline__ float wredsum(float v) {
  #pragma unroll
  for (int m = 1; m < 64; m <<= 1) v += __shfl_xor(v, m);
  return v;
}

// Coalesced wave matvec, full register preload: out[r] = W[r,:].lin, C=64.
template <int R>
__device__ __forceinline__ void matvec_pre(const float* __restrict__ W,
                                           const float* lin, float* lout,
                                           int lane) {
  const int g = lane >> 4, q = lane & 15;
  float4 w[R >> 2];
  #pragma unroll
  for (int rb = 0; rb < (R >> 2); ++rb)
    w[rb] = *reinterpret_cast<const float4*>(W + (rb * 4 + g) * 64 + 4 * q);
  const float4 iv = *reinterpret_cast<const float4*>(lin + 4 * q);
  #pragma unroll
  for (int rb = 0; rb < (R >> 2); ++rb) {
    float p = w[rb].x * iv.x + w[rb].y * iv.y + w[rb].z * iv.z + w[rb].w * iv.w;
    p += __shfl_xor(p, 1);
    p += __shfl_xor(p, 2);
    p += __shfl_xor(p, 4);
    p += __shfl_xor(p, 8);
    if (q == 0) lout[rb * 4 + g] = p;
  }
}

// Same, C=128.
template <int R>
__device__ __forceinline__ void matvec_pre_c128(const float* __restrict__ W,
                                                const float* lin, float* lout,
                                                int lane) {
  const int g = lane >> 4, q = lane & 15;
  float4 w0[R >> 2], w1[R >> 2];
  #pragma unroll
  for (int rb = 0; rb < (R >> 2); ++rb) {
    w0[rb] = *reinterpret_cast<const float4*>(W + (rb * 4 + g) * 128 + 4 * q);
    w1[rb] = *reinterpret_cast<const float4*>(W + (rb * 4 + g) * 128 + 64 + 4 * q);
  }
  const float4 iv0 = *reinterpret_cast<const float4*>(lin + 4 * q);
  const float4 iv1 = *reinterpret_cast<const float4*>(lin + 64 + 4 * q);
  #pragma unroll
  for (int rb = 0; rb < (R >> 2); ++rb) {
    float p = w0[rb].x * iv0.x + w0[rb].y * iv0.y + w0[rb].z * iv0.z + w0[rb].w * iv0.w
            + w1[rb].x * iv1.x + w1[rb].y * iv1.y + w1[rb].z * iv1.z + w1[rb].w * iv1.w;
    p += __shfl_xor(p, 1);
    p += __shfl_xor(p, 2);
    p += __shfl_xor(p, 4);
    p += __shfl_xor(p, 8);
    if (q == 0) lout[rb * 4 + g] = p;
  }
}

// ---------------------------------------------------------------------------
// KA: big pass over x — r5 body (60 VGPR, no spill), grid 1024, 16 iters.
// Changes vs r5/r8: (1) softmax WITHOUT max-subtraction (logits in log2
// domain bounded ~|8| << 126, exp2 cannot overflow); (2) epilogue writes
// per-block partials Up/Sp with plain coalesced stores — NO atomics.
// ---------------------------------------------------------------------------
__global__ __launch_bounds__(256, 2)
void ka_kernel(const float* __restrict__ x,
               const float* __restrict__ qtil,
               const float* __restrict__ cvec,
               float* __restrict__ Up, float* __restrict__ Sp) {
  const int b    = blockIdx.x >> 4;   // 16 row-blocks per batch
  const int rb   = blockIdx.x & 15;
  const int tid  = threadIdx.x;
  const int wave = tid >> 6;
  const int lane = tid & 63;
  const int c    = lane & 15;         // d-chunk index (4 floats)

  const float4* qt4 = reinterpret_cast<const float4*>(qtil + (size_t)b * NSLOT * D);
  float4 qf[NSLOT];
  float  cs[NSLOT];
  #pragma unroll
  for (int s = 0; s < NSLOT; ++s) {
    qf[s] = qt4[s * 16 + c];
    cs[s] = cvec[b * NSLOT + s];
  }

  float4 Ua[NSLOT];
  float  Sa[NSLOT];
  #pragma unroll
  for (int s = 0; s < NSLOT; ++s) { Ua[s] = make_float4(0.f, 0.f, 0.f, 0.f); Sa[s] = 0.f; }

  const float4* xb = reinterpret_cast<const float4*>(
      x + ((size_t)b * NROW + rb * 256 + wave * 64) * D);

  #pragma unroll 2
  for (int it = 0; it < 16; ++it) {
    float4 xv = xb[it * 64 + lane];  // 4 rows x 64 floats, fully coalesced

    // --- LayerNorm over the 16-lane group (row) ---
    float s1 = xv.x + xv.y + xv.z + xv.w;
    float s2 = xv.x * xv.x + xv.y * xv.y + xv.z * xv.z + xv.w * xv.w;
    #pragma unroll
    for (int m = 1; m < 16; m <<= 1) {
      s1 += __shfl_xor(s1, m);
      s2 += __shfl_xor(s2, m);
    }
    float mean = s1 * (1.f / 64.f);
    float var  = s2 * (1.f / 64.f) - mean * mean;
    float rstd = rsqrtf(var + EPS);
    float nb   = -mean * rstd;
    float4 xn;
    xn.x = fmaf(xv.x, rstd, nb);
    xn.y = fmaf(xv.y, rstd, nb);
    xn.z = fmaf(xv.z, rstd, nb);
    xn.w = fmaf(xv.w, rstd, nb);

    // --- logits (pre-scaled by 1/ln2 via SCK in q~/c) ---
    float p[NSLOT];
    #pragma unroll
    for (int s = 0; s < NSLOT; ++s)
      p[s] = xn.x * qf[s].x + xn.y * qf[s].y + xn.z * qf[s].z + xn.w * qf[s].w;
    #pragma unroll
    for (int m = 1; m < 16; m <<= 1) {
      #pragma unroll
      for (int s = 0; s < NSLOT; ++s) p[s] += __shfl_xor(p[s], m);
    }

    // --- softmax over 8 slots, no max-subtraction (bounded log2 logits) ---
    float sum = 0.f;
    #pragma unroll
    for (int s = 0; s < NSLOT; ++s) {
      p[s] = exp2f(p[s] + cs[s]);
      sum += p[s];
    }
    float inv = 1.f / sum;
    #pragma unroll
    for (int s = 0; s < NSLOT; ++s) {
      float a = p[s] * inv + 1e-8f;
      Sa[s] += a;
      Ua[s].x = fmaf(a, xn.x, Ua[s].x);
      Ua[s].y = fmaf(a, xn.y, Ua[s].y);
      Ua[s].z = fmaf(a, xn.z, Ua[s].z);
      Ua[s].w = fmaf(a, xn.w, Ua[s].w);
    }
  }

  // cross-group reduce within wave (masks 16, 32)
  #pragma unroll
  for (int m = 16; m < 64; m <<= 1) {
    #pragma unroll
    for (int s = 0; s < NSLOT; ++s) {
      Sa[s]   += __shfl_xor(Sa[s], m);
      Ua[s].x += __shfl_xor(Ua[s].x, m);
      Ua[s].y += __shfl_xor(Ua[s].y, m);
      Ua[s].z += __shfl_xor(Ua[s].z, m);
      Ua[s].w += __shfl_xor(Ua[s].w, m);
    }
  }

  __shared__ float lU[4][NSLOT][D];
  __shared__ float lS[4][NSLOT];
  if (lane < 16) {
    #pragma unroll
    for (int s = 0; s < NSLOT; ++s) {
      lU[wave][s][4 * c + 0] = Ua[s].x;
      lU[wave][s][4 * c + 1] = Ua[s].y;
      lU[wave][s][4 * c + 2] = Ua[s].z;
      lU[wave][s][4 * c + 3] = Ua[s].w;
    }
    if (c == 0) {
      #pragma unroll
      for (int s = 0; s < NSLOT; ++s) lS[wave][s] = Sa[s];
    }
  }
  __syncthreads();

  // plain coalesced partial stores (no atomics)
  for (int cell = tid; cell < NSLOT * D; cell += 256) {
    int s = cell >> 6, d = cell & 63;
    Up[((size_t)(b * NSLOT + s) * NP + rb) * D + d] =
        lU[0][s][d] + lU[1][s][d] + lU[2][s][d] + lU[3][s][d];
  }
  if (tid < NSLOT) {
    Sp[(b * NSLOT + tid) * NP + rb] =
        lS[0][tid] + lS[1][tid] + lS[2][tid] + lS[3][tid];
  }
}

// ---------------------------------------------------------------------------
// prep work (4 blocks of 128 thr, appended to the mode-0 kb launch):
//  pb0: Mt[d][e] = sum_f Wq[f][e]*Wk[f][d]; ct[d]=sum bq*Wk[:,d];
//       u[e]=sum bk*Wq[:,e]; c0 = bk.bq
//  pb1-3: G = Wih @ Wv (192x64); bias_i = Wih @ bv + bih
// ---------------------------------------------------------------------------
__device__ void prep_block(int pb,
                           const float* __restrict__ Wq, const float* __restrict__ bq,
                           const float* __restrict__ Wk, const float* __restrict__ bk,
                           const float* __restrict__ Wv, const float* __restrict__ bv,
                           const float* __restrict__ Wih, const float* __restrict__ bih,
                           float* __restrict__ Mt, float* __restrict__ ct,
                           float* __restrict__ u, float* __restrict__ c0,
                           float* __restrict__ G, float* __restrict__ bias_i) {
  const int t = threadIdx.x;  // 0..127
  float acc[32];
  #pragma unroll
  for (int j = 0; j < 32; ++j) acc[j] = 0.f;
  if (pb == 0) {
    const int row = t >> 1;
    const int cb  = (t & 1) * 32;
    for (int f = 0; f < 64; ++f) {
      float wkf = Wk[f * 64 + row];
      const float4* wq4 = reinterpret_cast<const float4*>(Wq + f * 64 + cb);
      #pragma unroll
      for (int j4 = 0; j4 < 8; ++j4) {
        float4 wq = wq4[j4];
        acc[4 * j4 + 0] = fmaf(wkf, wq.x, acc[4 * j4 + 0]);
        acc[4 * j4 + 1] = fmaf(wkf, wq.y, acc[4 * j4 + 1]);
        acc[4 * j4 + 2] = fmaf(wkf, wq.z, acc[4 * j4 + 2]);
        acc[4 * j4 + 3] = fmaf(wkf, wq.w, acc[4 * j4 + 3]);
      }
    }
    #pragma unroll
    for (int j = 0; j < 32; ++j) Mt[row * 64 + cb + j] = acc[j];
    if (t < 64) {
      float a = 0.f, bsum = 0.f;
      for (int f = 0; f < 64; ++f) {
        a    = fmaf(bq[f], Wk[f * 64 + t], a);
        bsum = fmaf(bk[f], Wq[f * 64 + t], bsum);
      }
      ct[t] = a;
      u[t]  = bsum;
    }
    if (t == 0) {
      float a = 0.f;
      for (int f = 0; f < 64; ++f) a = fmaf(bk[f], bq[f], a);
      c0[0] = a;
    }
  } else {
    const int r0  = (pb - 1) * 64;
    const int row = r0 + (t >> 1);
    const int cb  = (t & 1) * 32;
    for (int f = 0; f < 64; ++f) {
      float wih = Wih[row * 64 + f];
      const float4* wv4 = reinterpret_cast<const float4*>(Wv + f * 64 + cb);
      #pragma unroll
      for (int j4 = 0; j4 < 8; ++j4) {
        float4 wv = wv4[j4];
        acc[4 * j4 + 0] = fmaf(wih, wv.x, acc[4 * j4 + 0]);
        acc[4 * j4 + 1] = fmaf(wih, wv.y, acc[4 * j4 + 1]);
        acc[4 * j4 + 2] = fmaf(wih, wv.z, acc[4 * j4 + 2]);
        acc[4 * j4 + 3] = fmaf(wih, wv.w, acc[4 * j4 + 3]);
      }
    }
    #pragma unroll
    for (int j = 0; j < 32; ++j) G[row * 64 + cb + j] = acc[j];
    if (t < 64) {
      int rr = r0 + t;
      float a = bih[rr];
      for (int f = 0; f < 64; ++f) a = fmaf(Wih[rr * 64 + f], bv[f], a);
      bias_i[rr] = a;
    }
  }
}

// ---------------------------------------------------------------------------
// KB: per-(batch,slot), 128 threads = 2 waves. mode0: init slots + q~ via
// unfolded path. mode1: wave0 first reduces the NP partials (coalesced),
// then wave0 gi=G@ub || wave1 gh=Whh@h; GRU+LN; W1/W2/Mt split across waves.
// ---------------------------------------------------------------------------
__global__ __launch_bounds__(128, 1)
void kb_kernel(int mode, int last,
               const float* __restrict__ noise, const float* __restrict__ mu,
               const float* __restrict__ sigma,
               const float* __restrict__ Wq, const float* __restrict__ bq,
               const float* __restrict__ Wk, const float* __restrict__ bk,
               const float* __restrict__ Wv, const float* __restrict__ bv,
               const float* __restrict__ Wih, const float* __restrict__ bih,
               float* __restrict__ G, float* __restrict__ bias_i,
               const float* __restrict__ Whh, const float* __restrict__ bhh,
               const float* __restrict__ W1, const float* __restrict__ b1,
               const float* __restrict__ W2, const float* __restrict__ b2,
               float* __restrict__ Mt, float* __restrict__ ct,
               float* __restrict__ u, float* __restrict__ c0,
               float* __restrict__ slots, float* __restrict__ qtil,
               float* __restrict__ cvec, const float* __restrict__ Up,
               const float* __restrict__ Sp, float* __restrict__ out) {
  if (blockIdx.x >= NB * NSLOT) {  // prep blocks (mode-0 launch only)
    prep_block(blockIdx.x - NB * NSLOT, Wq, bq, Wk, bk, Wv, bv, Wih, bih,
               Mt, ct, u, c0, G, bias_i);
    return;
  }

  const int blk = blockIdx.x;
  const int b   = blk >> 3;
  const int s   = blk & 7;
  const int wv  = threadIdx.x >> 6;
  const int d   = threadIdx.x & 63;
  const int idx = (b * NSLOT + s) * D + d;

  __shared__ float bufA[64];
  __shared__ float bufQ[64];
  __shared__ float gi[192];
  __shared__ float gh[192];
  __shared__ float bufH[128];

  if (mode == 0) {
    if (wv == 0) {
      float h = mu[d] + sigma[d] * noise[idx];
      slots[idx] = h;
      // q~ unfolded: ln=LN(h); q=Wq@ln+bq; qt=q@Wk; c=bk.q (wave-local)
      float m  = wredsum(h) * (1.f / 64.f);
      float hc = h - m;
      float v  = wredsum(hc * hc) * (1.f / 64.f);
      float ln = hc * rsqrtf(v + EPS);
      bufA[d] = ln;
      matvec_pre<64>(Wq, bufA, gi, d);
      float qv = gi[d] + bq[d];
      bufQ[d] = qv;
      float qt0 = 0.f, qt1 = 0.f, qt2 = 0.f, qt3 = 0.f;
      #pragma unroll
      for (int e = 0; e < 64; e += 4) {
        const float4 qb = *reinterpret_cast<const float4*>(bufQ + e);
        qt0 = fmaf(Wk[(e + 0) * D + d], qb.x, qt0);
        qt1 = fmaf(Wk[(e + 1) * D + d], qb.y, qt1);
        qt2 = fmaf(Wk[(e + 2) * D + d], qb.z, qt2);
        qt3 = fmaf(Wk[(e + 3) * D + d], qb.w, qt3);
      }
      qtil[idx] = ((qt0 + qt1) + (qt2 + qt3)) * SCK;
      float ca = wredsum(bk[d] * qv) * SCK;
      if (d == 0) cvec[b * NSLOT + s] = ca;
    }
    return;
  }

  // ---- mode 1 ----
  float h = 0.f, sl = 0.f;
  if (wv == 0) {
    // reduce NP partials: ub = (sum_p Up)/(sum_p Sp) — coalesced loads
    const float* up = Up + (size_t)(b * NSLOT + s) * NP * D + d;
    float acc = 0.f;
    #pragma unroll
    for (int p = 0; p < NP; ++p) acc += up[p * D];
    const float* sp = Sp + (b * NSLOT + s) * NP;
    float ss = 0.f;
    #pragma unroll
    for (int p = 0; p < NP; ++p) ss += sp[p];   // wave-uniform scalar loads
    bufA[d] = acc / ss;
    h = slots[idx];
    bufH[d] = h;
  }
  __syncthreads();
  if (wv == 0) matvec_pre<192>(G,   bufA, gi, d);
  else         matvec_pre<192>(Whh, bufH, gh, d);
  __syncthreads();
  if (wv == 0) {
    float r  = 1.f / (1.f + expf(-(gi[d]        + bias_i[d]        + gh[d]        + bhh[d])));
    float z  = 1.f / (1.f + expf(-(gi[64 + d]   + bias_i[64 + d]   + gh[64 + d]   + bhh[64 + d])));
    float nn = tanhf(gi[128 + d] + bias_i[128 + d] + r * (gh[128 + d] + bhh[128 + d]));
    h = (1.f - z) * nn + z * h;
    float m  = wredsum(h) * (1.f / 64.f);
    float hc = h - m;
    float v  = wredsum(hc * hc) * (1.f / 64.f);
    sl = hc * rsqrtf(v + EPS);
    bufA[d] = sl;
  }
  __syncthreads();
  matvec_pre<64>(W1 + wv * 64 * 64, bufA, gi + wv * 64, d);
  __syncthreads();
  bufH[threadIdx.x] = fmaxf(gi[threadIdx.x] + b1[threadIdx.x], 0.f);
  __syncthreads();
  matvec_pre_c128<32>(W2 + wv * 32 * 128, bufH, gh + wv * 32, d);
  __syncthreads();
  if (wv == 0) {
    h = sl + gh[d] + b2[d];
    slots[idx] = h;
    if (last) out[idx] = h;
  }

  if (!last) {
    if (wv == 0) {
      float m  = wredsum(h) * (1.f / 64.f);
      float hc = h - m;
      float v  = wredsum(hc * hc) * (1.f / 64.f);
      float ln = hc * rsqrtf(v + EPS);
      bufA[d] = ln;
    }
    __syncthreads();
    matvec_pre<32>(Mt + wv * 32 * 64, bufA, gi + wv * 32, d);
    __syncthreads();
    if (wv == 0) {
      qtil[idx] = SCK * (gi[d] + ct[d]);
      float ca = (wredsum(u[d] * bufA[d]) + c0[0]) * SCK;
      if (d == 0) cvec[b * NSLOT + s] = ca;
    }
  }
}

// ---------------------------------------------------------------------------
extern "C" void kernel_launch(void* const* d_in, const int* in_sizes, int n_in,
                              void* d_out, int out_size, void* d_ws, size_t ws_size,
                              hipStream_t stream) {
  (void)in_sizes; (void)n_in; (void)out_size; (void)ws_size;
  const float* x     = (const float*)d_in[0];
  const float* noise = (const float*)d_in[1];
  const float* Wq    = (const float*)d_in[2];
  const float* bq    = (const float*)d_in[3];
  const float* Wk    = (const float*)d_in[4];
  const float* bk    = (const float*)d_in[5];
  const float* Wv    = (const float*)d_in[6];
  const float* bv    = (const float*)d_in[7];
  const float* Wih   = (const float*)d_in[8];
  const float* Whh   = (const float*)d_in[9];
  const float* bih   = (const float*)d_in[10];
  const float* bhh   = (const float*)d_in[11];
  const float* W1    = (const float*)d_in[12];
  const float* b1    = (const float*)d_in[13];
  const float* W2    = (const float*)d_in[14];
  const float* b2    = (const float*)d_in[15];
  const float* mu    = (const float*)d_in[16];
  const float* sigma = (const float*)d_in[17];

  float* ws     = (float*)d_ws;
  float* slots  = ws;           // 32768
  float* qtil   = ws + 32768;   // 32768
  float* cvec   = ws + 65536;   // 512
  float* Mt     = ws + 66048;   // 4096
  float* ct     = ws + 70144;   // 64
  float* uvec   = ws + 70208;   // 64
  float* c0     = ws + 70272;   // 16 (padded)
  float* G      = ws + 70288;   // 12288
  float* bias_i = ws + 82576;   // 192
  float* Up     = ws + 82768;   // 64*8*16*64 = 524288
  float* Sp     = ws + 607056;  // 8192  (total ~615K floats = 2.46 MB)
  float* out    = (float*)d_out;

  auto launch_kb = [&](int mode, int last, int nblk) {
    kb_kernel<<<nblk, 128, 0, stream>>>(mode, last, noise, mu, sigma,
                                        Wq, bq, Wk, bk, Wv, bv, Wih, bih,
                                        G, bias_i, Whh, bhh, W1, b1, W2, b2,
                                        Mt, ct, uvec, c0,
                                        slots, qtil, cvec, Up, Sp, out);
  };

  launch_kb(0, 0, NB * NSLOT + 4);  // init + q~ (unfolded) + prep blocks
  for (int it = 1; it <= 3; ++it) {
    ka_kernel<<<NB * NP, 256, 0, stream>>>(x, qtil, cvec, Up, Sp);
    launch_kb(1, it == 3 ? 1 : 0, NB * NSLOT);
  }
}

// Round 10
// 166.513 us; speedup vs baseline: 2.1011x; 1.2042x over previous
//
#include <hip/hip_runtime.h>
#include <math.h>

#define D     64
#define NSLOT 8
#define NB    64
#define NROW  4096
#define NP    16          // row-blocks (partials) per batch
#define EPS   1e-5f
#define LOG2E 1.44269504f
#define SCK   (0.125f * LOG2E)   // 1/sqrt(64) * 1/ln2, folded into q~ and c

typedef unsigned short ushortt;

// ---------------------------------------------------------------------------
// helpers
// ---------------------------------------------------------------------------
__device__ __forceinline__ float wredsum(float v) {
  #pragma unroll
  for (int m = 1; m < 64; m <<= 1) v += __shfl_xor(v, m);
  return v;
}

// Coalesced wave matvec, full register preload: out[r] = W[r,:].lin, C=64.
template <int R>
__device__ __forceinline__ void matvec_pre(const float* __restrict__ W,
                                           const float* lin, float* lout,
                                           int lane) {
  const int g = lane >> 4, q = lane & 15;
  float4 w[R >> 2];
  #pragma unroll
  for (int rb = 0; rb < (R >> 2); ++rb)
    w[rb] = *reinterpret_cast<const float4*>(W + (rb * 4 + g) * 64 + 4 * q);
  const float4 iv = *reinterpret_cast<const float4*>(lin + 4 * q);
  #pragma unroll
  for (int rb = 0; rb < (R >> 2); ++rb) {
    float p = w[rb].x * iv.x + w[rb].y * iv.y + w[rb].z * iv.z + w[rb].w * iv.w;
    p += __shfl_xor(p, 1);
    p += __shfl_xor(p, 2);
    p += __shfl_xor(p, 4);
    p += __shfl_xor(p, 8);
    if (q == 0) lout[rb * 4 + g] = p;
  }
}

// Same, C=128.
template <int R>
__device__ __forceinline__ void matvec_pre_c128(const float* __restrict__ W,
                                                const float* lin, float* lout,
                                                int lane) {
  const int g = lane >> 4, q = lane & 15;
  float4 w0[R >> 2], w1[R >> 2];
  #pragma unroll
  for (int rb = 0; rb < (R >> 2); ++rb) {
    w0[rb] = *reinterpret_cast<const float4*>(W + (rb * 4 + g) * 128 + 4 * q);
    w1[rb] = *reinterpret_cast<const float4*>(W + (rb * 4 + g) * 128 + 64 + 4 * q);
  }
  const float4 iv0 = *reinterpret_cast<const float4*>(lin + 4 * q);
  const float4 iv1 = *reinterpret_cast<const float4*>(lin + 64 + 4 * q);
  #pragma unroll
  for (int rb = 0; rb < (R >> 2); ++rb) {
    float p = w0[rb].x * iv0.x + w0[rb].y * iv0.y + w0[rb].z * iv0.z + w0[rb].w * iv0.w
            + w1[rb].x * iv1.x + w1[rb].y * iv1.y + w1[rb].z * iv1.z + w1[rb].w * iv1.w;
    p += __shfl_xor(p, 1);
    p += __shfl_xor(p, 2);
    p += __shfl_xor(p, 4);
    p += __shfl_xor(p, 8);
    if (q == 0) lout[rb * 4 + g] = p;
  }
}

// ---------------------------------------------------------------------------
// KA: big pass over x. PASS=0: LN from x, no cache store. PASS=1: LN from x,
// store xn as bf16. PASS=2: load bf16 xn, skip LN.
// Inner loop: distributed-owner logit reduce (lane (l>>1)&7 owns one slot;
// r7-verified), 1 exp2/lane softmax (no max-sub, log2-domain bounded),
// bpermute broadcast, rank-8 accumulate. q~ in LDS. Partial-store epilogue.
// ---------------------------------------------------------------------------
template <int PASS>
__global__ __launch_bounds__(256, 2)
void ka_kernel(const float* __restrict__ x,
               const ushortt* __restrict__ xnbi,
               ushortt* __restrict__ xnbo,
               const float* __restrict__ qtil,
               const float* __restrict__ cvec,
               float* __restrict__ Up, float* __restrict__ Sp) {
  const int b    = blockIdx.x >> 4;   // 16 row-blocks per batch
  const int rb   = blockIdx.x & 15;
  const int tid  = threadIdx.x;
  const int wave = tid >> 6;
  const int lane = tid & 63;
  const int c    = lane & 15;         // d-chunk index (4 floats)
  const int sown = (lane >> 1) & 7;   // slot owned in distributed reduce

  __shared__ float qs[NSLOT * D];
  __shared__ float lU[4][NSLOT][D];
  __shared__ float lS[4][NSLOT];

  if (tid < 128)
    reinterpret_cast<float4*>(qs)[tid] =
        reinterpret_cast<const float4*>(qtil + (size_t)b * NSLOT * D)[tid];
  const float cs_own = cvec[b * NSLOT + sown];
  __syncthreads();
  const float4* qs4 = reinterpret_cast<const float4*>(qs);

  float4 Ua[NSLOT];
  #pragma unroll
  for (int s = 0; s < NSLOT; ++s) Ua[s] = make_float4(0.f, 0.f, 0.f, 0.f);
  float Sa = 0.f;

  const size_t rowbase = (size_t)b * NROW + rb * 256 + wave * 64;
  const float4*   xb = reinterpret_cast<const float4*>(x) + rowbase * 16;
  const ushort4*  xi = reinterpret_cast<const ushort4*>(xnbi) + rowbase * 16;
  ushort4*        xo = reinterpret_cast<ushort4*>(xnbo) + rowbase * 16;

  #pragma unroll 2
  for (int it = 0; it < 16; ++it) {
    float4 xn;
    if (PASS == 2) {
      ushort4 v = xi[it * 64 + lane];
      xn.x = __uint_as_float((unsigned)v.x << 16);
      xn.y = __uint_as_float((unsigned)v.y << 16);
      xn.z = __uint_as_float((unsigned)v.z << 16);
      xn.w = __uint_as_float((unsigned)v.w << 16);
    } else {
      float4 xv = xb[it * 64 + lane];  // 4 rows x 64 floats, coalesced
      float s1 = xv.x + xv.y + xv.z + xv.w;
      float s2 = xv.x * xv.x + xv.y * xv.y + xv.z * xv.z + xv.w * xv.w;
      #pragma unroll
      for (int m = 1; m < 16; m <<= 1) {
        s1 += __shfl_xor(s1, m);
        s2 += __shfl_xor(s2, m);
      }
      float mean = s1 * (1.f / 64.f);
      float var  = s2 * (1.f / 64.f) - mean * mean;
      float rstd = rsqrtf(var + EPS);
      float nb   = -mean * rstd;
      xn.x = fmaf(xv.x, rstd, nb);
      xn.y = fmaf(xv.y, rstd, nb);
      xn.z = fmaf(xv.z, rstd, nb);
      xn.w = fmaf(xv.w, rstd, nb);
      if (PASS == 1) {
        ushort4 o;
        o.x = (ushortt)((__float_as_uint(xn.x) + 0x8000u) >> 16);
        o.y = (ushortt)((__float_as_uint(xn.y) + 0x8000u) >> 16);
        o.z = (ushortt)((__float_as_uint(xn.z) + 0x8000u) >> 16);
        o.w = (ushortt)((__float_as_uint(xn.w) + 0x8000u) >> 16);
        xo[it * 64 + lane] = o;
      }
    }

    // partial dots (lane's 4 d's, all 8 slots; q~ broadcast from LDS)
    float p[NSLOT];
    #pragma unroll
    for (int s = 0; s < NSLOT; ++s) {
      float4 qv = qs4[s * 16 + c];
      p[s] = xn.x * qv.x + xn.y * qv.y + xn.z * qv.z + xn.w * qv.w;
    }

    // distributed butterfly: lane ends owning slot sown's full group-sum
    const bool h3 = (lane & 8) != 0;
    float t0 = __shfl_xor(p[0], 8), t1 = __shfl_xor(p[1], 8);
    float t2 = __shfl_xor(p[2], 8), t3 = __shfl_xor(p[3], 8);
    float t4 = __shfl_xor(p[4], 8), t5 = __shfl_xor(p[5], 8);
    float t6 = __shfl_xor(p[6], 8), t7 = __shfl_xor(p[7], 8);
    float r0 = (h3 ? p[4] : p[0]) + (h3 ? t4 : t0);
    float r1 = (h3 ? p[5] : p[1]) + (h3 ? t5 : t1);
    float r2 = (h3 ? p[6] : p[2]) + (h3 ? t6 : t2);
    float r3 = (h3 ? p[7] : p[3]) + (h3 ? t7 : t3);
    const bool h2 = (lane & 4) != 0;
    float u0 = __shfl_xor(r0, 4), u1 = __shfl_xor(r1, 4);
    float u2 = __shfl_xor(r2, 4), u3 = __shfl_xor(r3, 4);
    float v0 = (h2 ? r2 : r0) + (h2 ? u2 : u0);
    float v1 = (h2 ? r3 : r1) + (h2 ? u3 : u1);
    const bool h1 = (lane & 2) != 0;
    float w0 = __shfl_xor(v0, 2), w1 = __shfl_xor(v1, 2);
    float z  = (h1 ? v1 : v0) + (h1 ? w1 : w0);
    z += __shfl_xor(z, 1);

    // softmax across slot-owner lanes (no max-sub; bounded log2 logits)
    float e = exp2f(z + cs_own);
    float sum = e;
    sum += __shfl_xor(sum, 2);
    sum += __shfl_xor(sum, 4);
    sum += __shfl_xor(sum, 8);
    float a_own = e * (1.f / sum) + 1e-8f;
    Sa += a_own;

    // broadcast a[s] to the whole group, rank-8 accumulate
    const int gb = lane & 48;
    #pragma unroll
    for (int s = 0; s < NSLOT; ++s) {
      float as = __shfl(a_own, gb + 2 * s);
      Ua[s].x = fmaf(as, xn.x, Ua[s].x);
      Ua[s].y = fmaf(as, xn.y, Ua[s].y);
      Ua[s].z = fmaf(as, xn.z, Ua[s].z);
      Ua[s].w = fmaf(as, xn.w, Ua[s].w);
    }
  }

  // cross-group reduce (masks 16,32)
  #pragma unroll
  for (int m = 16; m < 64; m <<= 1) {
    Sa += __shfl_xor(Sa, m);
    #pragma unroll
    for (int s = 0; s < NSLOT; ++s) {
      Ua[s].x += __shfl_xor(Ua[s].x, m);
      Ua[s].y += __shfl_xor(Ua[s].y, m);
      Ua[s].z += __shfl_xor(Ua[s].z, m);
      Ua[s].w += __shfl_xor(Ua[s].w, m);
    }
  }

  if (lane < 16) {
    #pragma unroll
    for (int s = 0; s < NSLOT; ++s) {
      lU[wave][s][4 * c + 0] = Ua[s].x;
      lU[wave][s][4 * c + 1] = Ua[s].y;
      lU[wave][s][4 * c + 2] = Ua[s].z;
      lU[wave][s][4 * c + 3] = Ua[s].w;
    }
    if ((lane & 1) == 0) lS[wave][lane >> 1] = Sa;  // even lane 2s owns slot s
  }
  __syncthreads();

  // plain coalesced partial stores (no atomics)
  for (int cell = tid; cell < NSLOT * D; cell += 256) {
    int s = cell >> 6, d = cell & 63;
    Up[((size_t)(b * NSLOT + s) * NP + rb) * D + d] =
        lU[0][s][d] + lU[1][s][d] + lU[2][s][d] + lU[3][s][d];
  }
  if (tid < NSLOT) {
    Sp[(b * NSLOT + tid) * NP + rb] =
        lS[0][tid] + lS[1][tid] + lS[2][tid] + lS[3][tid];
  }
}

// ---------------------------------------------------------------------------
// prep work (4 blocks of 128 thr, appended to the mode-0 kb launch)
// ---------------------------------------------------------------------------
__device__ void prep_block(int pb,
                           const float* __restrict__ Wq, const float* __restrict__ bq,
                           const float* __restrict__ Wk, const float* __restrict__ bk,
                           const float* __restrict__ Wv, const float* __restrict__ bv,
                           const float* __restrict__ Wih, const float* __restrict__ bih,
                           float* __restrict__ Mt, float* __restrict__ ct,
                           float* __restrict__ u, float* __restrict__ c0,
                           float* __restrict__ G, float* __restrict__ bias_i) {
  const int t = threadIdx.x;  // 0..127
  float acc[32];
  #pragma unroll
  for (int j = 0; j < 32; ++j) acc[j] = 0.f;
  if (pb == 0) {
    const int row = t >> 1;
    const int cb  = (t & 1) * 32;
    for (int f = 0; f < 64; ++f) {
      float wkf = Wk[f * 64 + row];
      const float4* wq4 = reinterpret_cast<const float4*>(Wq + f * 64 + cb);
      #pragma unroll
      for (int j4 = 0; j4 < 8; ++j4) {
        float4 wq = wq4[j4];
        acc[4 * j4 + 0] = fmaf(wkf, wq.x, acc[4 * j4 + 0]);
        acc[4 * j4 + 1] = fmaf(wkf, wq.y, acc[4 * j4 + 1]);
        acc[4 * j4 + 2] = fmaf(wkf, wq.z, acc[4 * j4 + 2]);
        acc[4 * j4 + 3] = fmaf(wkf, wq.w, acc[4 * j4 + 3]);
      }
    }
    #pragma unroll
    for (int j = 0; j < 32; ++j) Mt[row * 64 + cb + j] = acc[j];
    if (t < 64) {
      float a = 0.f, bsum = 0.f;
      for (int f = 0; f < 64; ++f) {
        a    = fmaf(bq[f], Wk[f * 64 + t], a);
        bsum = fmaf(bk[f], Wq[f * 64 + t], bsum);
      }
      ct[t] = a;
      u[t]  = bsum;
    }
    if (t == 0) {
      float a = 0.f;
      for (int f = 0; f < 64; ++f) a = fmaf(bk[f], bq[f], a);
      c0[0] = a;
    }
  } else {
    const int r0  = (pb - 1) * 64;
    const int row = r0 + (t >> 1);
    const int cb  = (t & 1) * 32;
    for (int f = 0; f < 64; ++f) {
      float wih = Wih[row * 64 + f];
      const float4* wv4 = reinterpret_cast<const float4*>(Wv + f * 64 + cb);
      #pragma unroll
      for (int j4 = 0; j4 < 8; ++j4) {
        float4 wv = wv4[j4];
        acc[4 * j4 + 0] = fmaf(wih, wv.x, acc[4 * j4 + 0]);
        acc[4 * j4 + 1] = fmaf(wih, wv.y, acc[4 * j4 + 1]);
        acc[4 * j4 + 2] = fmaf(wih, wv.z, acc[4 * j4 + 2]);
        acc[4 * j4 + 3] = fmaf(wih, wv.w, acc[4 * j4 + 3]);
      }
    }
    #pragma unroll
    for (int j = 0; j < 32; ++j) G[row * 64 + cb + j] = acc[j];
    if (t < 64) {
      int rr = r0 + t;
      float a = bih[rr];
      for (int f = 0; f < 64; ++f) a = fmaf(Wih[rr * 64 + f], bv[f], a);
      bias_i[rr] = a;
    }
  }
}

// ---------------------------------------------------------------------------
// KB: per-(batch,slot), 128 threads = 2 waves (unchanged from r9).
// ---------------------------------------------------------------------------
__global__ __launch_bounds__(128, 1)
void kb_kernel(int mode, int last,
               const float* __restrict__ noise, const float* __restrict__ mu,
               const float* __restrict__ sigma,
               const float* __restrict__ Wq, const float* __restrict__ bq,
               const float* __restrict__ Wk, const float* __restrict__ bk,
               const float* __restrict__ Wv, const float* __restrict__ bv,
               const float* __restrict__ Wih, const float* __restrict__ bih,
               float* __restrict__ G, float* __restrict__ bias_i,
               const float* __restrict__ Whh, const float* __restrict__ bhh,
               const float* __restrict__ W1, const float* __restrict__ b1,
               const float* __restrict__ W2, const float* __restrict__ b2,
               float* __restrict__ Mt, float* __restrict__ ct,
               float* __restrict__ u, float* __restrict__ c0,
               float* __restrict__ slots, float* __restrict__ qtil,
               float* __restrict__ cvec, const float* __restrict__ Up,
               const float* __restrict__ Sp, float* __restrict__ out) {
  if (blockIdx.x >= NB * NSLOT) {  // prep blocks (mode-0 launch only)
    prep_block(blockIdx.x - NB * NSLOT, Wq, bq, Wk, bk, Wv, bv, Wih, bih,
               Mt, ct, u, c0, G, bias_i);
    return;
  }

  const int blk = blockIdx.x;
  const int b   = blk >> 3;
  const int s   = blk & 7;
  const int wv  = threadIdx.x >> 6;
  const int d   = threadIdx.x & 63;
  const int idx = (b * NSLOT + s) * D + d;

  __shared__ float bufA[64];
  __shared__ float bufQ[64];
  __shared__ float gi[192];
  __shared__ float gh[192];
  __shared__ float bufH[128];

  if (mode == 0) {
    if (wv == 0) {
      float h = mu[d] + sigma[d] * noise[idx];
      slots[idx] = h;
      float m  = wredsum(h) * (1.f / 64.f);
      float hc = h - m;
      float v  = wredsum(hc * hc) * (1.f / 64.f);
      float ln = hc * rsqrtf(v + EPS);
      bufA[d] = ln;
      matvec_pre<64>(Wq, bufA, gi, d);
      float qv = gi[d] + bq[d];
      bufQ[d] = qv;
      float qt0 = 0.f, qt1 = 0.f, qt2 = 0.f, qt3 = 0.f;
      #pragma unroll
      for (int e = 0; e < 64; e += 4) {
        const float4 qb = *reinterpret_cast<const float4*>(bufQ + e);
        qt0 = fmaf(Wk[(e + 0) * D + d], qb.x, qt0);
        qt1 = fmaf(Wk[(e + 1) * D + d], qb.y, qt1);
        qt2 = fmaf(Wk[(e + 2) * D + d], qb.z, qt2);
        qt3 = fmaf(Wk[(e + 3) * D + d], qb.w, qt3);
      }
      qtil[idx] = ((qt0 + qt1) + (qt2 + qt3)) * SCK;
      float ca = wredsum(bk[d] * qv) * SCK;
      if (d == 0) cvec[b * NSLOT + s] = ca;
    }
    return;
  }

  // ---- mode 1 ----
  float h = 0.f, sl = 0.f;
  if (wv == 0) {
    const float* up = Up + (size_t)(b * NSLOT + s) * NP * D + d;
    float acc = 0.f;
    #pragma unroll
    for (int p = 0; p < NP; ++p) acc += up[p * D];
    const float* sp = Sp + (b * NSLOT + s) * NP;
    float ss = 0.f;
    #pragma unroll
    for (int p = 0; p < NP; ++p) ss += sp[p];
    bufA[d] = acc / ss;
    h = slots[idx];
    bufH[d] = h;
  }
  __syncthreads();
  if (wv == 0) matvec_pre<192>(G,   bufA, gi, d);
  else         matvec_pre<192>(Whh, bufH, gh, d);
  __syncthreads();
  if (wv == 0) {
    float r  = 1.f / (1.f + expf(-(gi[d]        + bias_i[d]        + gh[d]        + bhh[d])));
    float z  = 1.f / (1.f + expf(-(gi[64 + d]   + bias_i[64 + d]   + gh[64 + d]   + bhh[64 + d])));
    float nn = tanhf(gi[128 + d] + bias_i[128 + d] + r * (gh[128 + d] + bhh[128 + d]));
    h = (1.f - z) * nn + z * h;
    float m  = wredsum(h) * (1.f / 64.f);
    float hc = h - m;
    float v  = wredsum(hc * hc) * (1.f / 64.f);
    sl = hc * rsqrtf(v + EPS);
    bufA[d] = sl;
  }
  __syncthreads();
  matvec_pre<64>(W1 + wv * 64 * 64, bufA, gi + wv * 64, d);
  __syncthreads();
  bufH[threadIdx.x] = fmaxf(gi[threadIdx.x] + b1[threadIdx.x], 0.f);
  __syncthreads();
  matvec_pre_c128<32>(W2 + wv * 32 * 128, bufH, gh + wv * 32, d);
  __syncthreads();
  if (wv == 0) {
    h = sl + gh[d] + b2[d];
    slots[idx] = h;
    if (last) out[idx] = h;
  }

  if (!last) {
    if (wv == 0) {
      float m  = wredsum(h) * (1.f / 64.f);
      float hc = h - m;
      float v  = wredsum(hc * hc) * (1.f / 64.f);
      float ln = hc * rsqrtf(v + EPS);
      bufA[d] = ln;
    }
    __syncthreads();
    matvec_pre<32>(Mt + wv * 32 * 64, bufA, gi + wv * 32, d);
    __syncthreads();
    if (wv == 0) {
      qtil[idx] = SCK * (gi[d] + ct[d]);
      float ca = (wredsum(u[d] * bufA[d]) + c0[0]) * SCK;
      if (d == 0) cvec[b * NSLOT + s] = ca;
    }
  }
}

// ---------------------------------------------------------------------------
extern "C" void kernel_launch(void* const* d_in, const int* in_sizes, int n_in,
                              void* d_out, int out_size, void* d_ws, size_t ws_size,
                              hipStream_t stream) {
  (void)in_sizes; (void)n_in; (void)out_size;
  const float* x     = (const float*)d_in[0];
  const float* noise = (const float*)d_in[1];
  const float* Wq    = (const float*)d_in[2];
  const float* bq    = (const float*)d_in[3];
  const float* Wk    = (const float*)d_in[4];
  const float* bk    = (const float*)d_in[5];
  const float* Wv    = (const float*)d_in[6];
  const float* bv    = (const float*)d_in[7];
  const float* Wih   = (const float*)d_in[8];
  const float* Whh   = (const float*)d_in[9];
  const float* bih   = (const float*)d_in[10];
  const float* bhh   = (const float*)d_in[11];
  const float* W1    = (const float*)d_in[12];
  const float* b1    = (const float*)d_in[13];
  const float* W2    = (const float*)d_in[14];
  const float* b2    = (const float*)d_in[15];
  const float* mu    = (const float*)d_in[16];
  const float* sigma = (const float*)d_in[17];

  float* ws     = (float*)d_ws;
  float* slots  = ws;           // 32768
  float* qtil   = ws + 32768;   // 32768
  float* cvec   = ws + 65536;   // 512
  float* Mt     = ws + 66048;   // 4096
  float* ct     = ws + 70144;   // 64
  float* uvec   = ws + 70208;   // 64
  float* c0     = ws + 70272;   // 16 (padded)
  float* G      = ws + 70288;   // 12288
  float* bias_i = ws + 82576;   // 192
  float* Up     = ws + 82768;   // 64*8*16*64 = 524288
  float* Sp     = ws + 607056;  // 8192 -> end 615248
  ushortt* xnb  = (ushortt*)(ws + 615296);  // 16.78M ushort = 33.5 MB
  float* out    = (float*)d_out;

  const bool use_xnb =
      ws_size >= (size_t)(615296 + 8388608) * sizeof(float);

  auto launch_kb = [&](int mode, int last, int nblk) {
    kb_kernel<<<nblk, 128, 0, stream>>>(mode, last, noise, mu, sigma,
                                        Wq, bq, Wk, bk, Wv, bv, Wih, bih,
                                        G, bias_i, Whh, bhh, W1, b1, W2, b2,
                                        Mt, ct, uvec, c0,
                                        slots, qtil, cvec, Up, Sp, out);
  };

  launch_kb(0, 0, NB * NSLOT + 4);  // init + q~ (unfolded) + prep blocks
  for (int it = 1; it <= 3; ++it) {
    if (!use_xnb) {
      ka_kernel<0><<<NB * NP, 256, 0, stream>>>(x, xnb, xnb, qtil, cvec, Up, Sp);
    } else if (it == 1) {
      ka_kernel<1><<<NB * NP, 256, 0, stream>>>(x, xnb, xnb, qtil, cvec, Up, Sp);
    } else {
      ka_kernel<2><<<NB * NP, 256, 0, stream>>>(x, xnb, xnb, qtil, cvec, Up, Sp);
    }
    launch_kb(1, it == 3 ? 1 : 0, NB * NSLOT);
  }
}

// Round 11
// 120.417 us; speedup vs baseline: 2.9054x; 1.3828x over previous
//
#include <hip/hip_runtime.h>
#include <math.h>

#define D     64
#define NSLOT 8
#define NB    64
#define NROW  4096
#define NP    16          // row-blocks (partials) per batch
#define EPS   1e-5f
#define SCK   (0.125f * 1.44269504f)   // 1/sqrt(64) * 1/ln2 folded into q~ and c

typedef unsigned short ushortt;
typedef __attribute__((ext_vector_type(8))) short bf16x8;
typedef __attribute__((ext_vector_type(4))) short short4v;
typedef __attribute__((ext_vector_type(4))) float f32x4;

__device__ __forceinline__ unsigned short f2bf(float f) {
  return (unsigned short)((__float_as_uint(f) + 0x8000u) >> 16);
}
__device__ __forceinline__ float bf2f(unsigned short v) {
  return __uint_as_float((unsigned)v << 16);
}

__device__ __forceinline__ float wredsum(float v) {
  #pragma unroll
  for (int m = 1; m < 64; m <<= 1) v += __shfl_xor(v, m);
  return v;
}

// Coalesced wave matvec, full register preload: out[r] = W[r,:].lin, C=64.
template <int R>
__device__ __forceinline__ void matvec_pre(const float* __restrict__ W,
                                           const float* lin, float* lout,
                                           int lane) {
  const int g = lane >> 4, q = lane & 15;
  float4 w[R >> 2];
  #pragma unroll
  for (int rb = 0; rb < (R >> 2); ++rb)
    w[rb] = *reinterpret_cast<const float4*>(W + (rb * 4 + g) * 64 + 4 * q);
  const float4 iv = *reinterpret_cast<const float4*>(lin + 4 * q);
  #pragma unroll
  for (int rb = 0; rb < (R >> 2); ++rb) {
    float p = w[rb].x * iv.x + w[rb].y * iv.y + w[rb].z * iv.z + w[rb].w * iv.w;
    p += __shfl_xor(p, 1);
    p += __shfl_xor(p, 2);
    p += __shfl_xor(p, 4);
    p += __shfl_xor(p, 8);
    if (q == 0) lout[rb * 4 + g] = p;
  }
}

template <int R>
__device__ __forceinline__ void matvec_pre_c128(const float* __restrict__ W,
                                                const float* lin, float* lout,
                                                int lane) {
  const int g = lane >> 4, q = lane & 15;
  float4 w0[R >> 2], w1[R >> 2];
  #pragma unroll
  for (int rb = 0; rb < (R >> 2); ++rb) {
    w0[rb] = *reinterpret_cast<const float4*>(W + (rb * 4 + g) * 128 + 4 * q);
    w1[rb] = *reinterpret_cast<const float4*>(W + (rb * 4 + g) * 128 + 64 + 4 * q);
  }
  const float4 iv0 = *reinterpret_cast<const float4*>(lin + 4 * q);
  const float4 iv1 = *reinterpret_cast<const float4*>(lin + 64 + 4 * q);
  #pragma unroll
  for (int rb = 0; rb < (R >> 2); ++rb) {
    float p = w0[rb].x * iv0.x + w0[rb].y * iv0.y + w0[rb].z * iv0.z + w0[rb].w * iv0.w
            + w1[rb].x * iv1.x + w1[rb].y * iv1.y + w1[rb].z * iv1.z + w1[rb].w * iv1.w;
    p += __shfl_xor(p, 1);
    p += __shfl_xor(p, 2);
    p += __shfl_xor(p, 4);
    p += __shfl_xor(p, 8);
    if (q == 0) lout[rb * 4 + g] = p;
  }
}

// ---------------------------------------------------------------------------
// KAM: MFMA pass over x. Per wave: 2 tiles of 32 rows.
//   logits S^T = mfma(q~A, Xn^T_B) twice (K=64) -> lane holds 4 slots of row
//   (l&15); softmax in-register + one shfl_xor(16); attn^T packed to LDS;
//   U += mfma(attn^T_A, Xn_B) x4 N-tiles. Xn staged [d][r] in LDS (stride 40
//   elems = 80B, 16B-aligned b128 reads, bank-spread).
// PASS=1: LN from fp32 x via 16-lane groups -> bf16 via LDS [r][d] (stride 72)
//         -> B-frags + linear fragment-layout store to xnb.
// PASS=2: B-frags loaded straight from xnb (64x16B linear per wave).
// Epilogue: per-block partial stores Up/Sp (no atomics), as r10.
// ---------------------------------------------------------------------------
template <int PASS>
__global__ __launch_bounds__(256)
void kam_kernel(const float* __restrict__ x,
                ushortt* __restrict__ xnb, int store,
                const float* __restrict__ qtil,
                const float* __restrict__ cvec,
                float* __restrict__ Up, float* __restrict__ Sp) {
  extern __shared__ char smem[];
  const int b    = blockIdx.x >> 4;
  const int rb   = blockIdx.x & 15;
  const int tid  = threadIdx.x;
  const int w    = tid >> 6;
  const int lane = tid & 63;
  const int sl   = lane & 15;
  const int g    = lane >> 4;

  short* Xdr = (short*)smem + w * (64 * 40);             // [d][r], stride 40
  short* sA  = (short*)(smem + 20480) + w * (16 * 40);   // [s][r], stride 40
  float* lU  = (float*)(smem + 25600);                   // [4][8][64]
  float* lS  = (float*)(smem + 33792);                   // [4][8]
  short* Xrd = (short*)(smem + 33920) + w * (32 * 72);   // PASS1 [r][d], stride 72

  // zero sA once: rows s=8..15 stay zero (A-operand padding)
  #pragma unroll
  for (int k = 0; k < 10; ++k) sA[k * 64 + lane] = 0;

  // q~ A-fragments (bf16; slots 8..15 zero). A[m][k]: m=lane&15, k=(lane>>4)*8+j
  bf16x8 qA[2];
  #pragma unroll
  for (int kh = 0; kh < 2; ++kh) {
    if (sl < 8) {
      const float* qp = qtil + (size_t)(b * NSLOT + sl) * D + kh * 32 + g * 8;
      #pragma unroll
      for (int j = 0; j < 8; ++j) qA[kh][j] = (short)f2bf(qp[j]);
    } else {
      #pragma unroll
      for (int j = 0; j < 8; ++j) qA[kh][j] = 0;
    }
  }
  float creg[4];
  #pragma unroll
  for (int r = 0; r < 4; ++r)
    creg[r] = (g < 2) ? cvec[b * NSLOT + 4 * g + r] : 0.f;

  f32x4 C[4];
  #pragma unroll
  for (int nt = 0; nt < 4; ++nt) C[nt] = (f32x4){0.f, 0.f, 0.f, 0.f};
  float Sa[4] = {0.f, 0.f, 0.f, 0.f};

  #pragma unroll
  for (int t = 0; t < 2; ++t) {
    const int tileIdx = (b * NP + rb) * 8 + w * 2 + t;   // 32-row tiles, global id
    bf16x8 Bx[2][2];

    if (PASS == 1) {
      const int rowbase = b * NROW + rb * 256 + w * 64 + t * 32;
      #pragma unroll
      for (int i = 0; i < 8; ++i) {
        const int lr = i * 4 + g;
        const float4 xv =
            reinterpret_cast<const float4*>(x)[(size_t)(rowbase + lr) * 16 + sl];
        float s1 = xv.x + xv.y + xv.z + xv.w;
        float s2 = xv.x * xv.x + xv.y * xv.y + xv.z * xv.z + xv.w * xv.w;
        #pragma unroll
        for (int m = 1; m < 16; m <<= 1) {
          s1 += __shfl_xor(s1, m);
          s2 += __shfl_xor(s2, m);
        }
        float mean = s1 * (1.f / 64.f);
        float var  = s2 * (1.f / 64.f) - mean * mean;
        float rstd = rsqrtf(var + EPS);
        float nb   = -mean * rstd;
        short4v p;
        p[0] = (short)f2bf(fmaf(xv.x, rstd, nb));
        p[1] = (short)f2bf(fmaf(xv.y, rstd, nb));
        p[2] = (short)f2bf(fmaf(xv.z, rstd, nb));
        p[3] = (short)f2bf(fmaf(xv.w, rstd, nb));
        *reinterpret_cast<short4v*>(&Xrd[lr * 72 + 4 * sl]) = p;
      }
      #pragma unroll
      for (int h = 0; h < 2; ++h)
        #pragma unroll
        for (int kh = 0; kh < 2; ++kh) {
          Bx[h][kh] =
              *reinterpret_cast<bf16x8*>(&Xrd[(h * 16 + sl) * 72 + kh * 32 + g * 8]);
          if (store)
            reinterpret_cast<bf16x8*>(xnb)[((size_t)tileIdx * 4 + h * 2 + kh) * 64 + lane] =
                Bx[h][kh];
        }
    } else {
      #pragma unroll
      for (int h = 0; h < 2; ++h)
        #pragma unroll
        for (int kh = 0; kh < 2; ++kh)
          Bx[h][kh] = reinterpret_cast<const bf16x8*>(
              xnb)[((size_t)tileIdx * 4 + h * 2 + kh) * 64 + lane];
    }

    // scatter xn -> Xdr [d][r]  (lane holds row h*16+sl, d = kh*32+g*8+j)
    #pragma unroll
    for (int h = 0; h < 2; ++h)
      #pragma unroll
      for (int kh = 0; kh < 2; ++kh)
        #pragma unroll
        for (int j = 0; j < 8; ++j)
          Xdr[(kh * 32 + g * 8 + j) * 40 + h * 16 + sl] = Bx[h][kh][j];

    // logits + softmax + attn^T pack, per 16-row half
    #pragma unroll
    for (int h = 0; h < 2; ++h) {
      f32x4 Dh = (f32x4){0.f, 0.f, 0.f, 0.f};
      Dh = __builtin_amdgcn_mfma_f32_16x16x32_bf16(qA[0], Bx[h][0], Dh, 0, 0, 0);
      Dh = __builtin_amdgcn_mfma_f32_16x16x32_bf16(qA[1], Bx[h][1], Dh, 0, 0, 0);
      // lane: row r = sl, slots s = 4*g+reg (valid g<2). log2-domain, no max-sub.
      float e[4];
      float z = 0.f;
      #pragma unroll
      for (int r = 0; r < 4; ++r) {
        e[r] = (g < 2) ? exp2f(Dh[r] + creg[r]) : 0.f;
        z += e[r];
      }
      z += __shfl_xor(z, 16);   // combine slot-groups 0+1 (2+3 garbage, unused)
      float inv = 1.f / z;
      #pragma unroll
      for (int r = 0; r < 4; ++r) {
        float a = e[r] * inv + 1e-8f;
        unsigned short ab = f2bf(a);
        Sa[r] += bf2f(ab);      // same rounded value as used in MFMA
        if (g < 2) sA[(4 * g + r) * 40 + h * 16 + sl] = (short)ab;
      }
    }

    // update MFMAs: A = attn^T [s][r], B = Xn [r][d]
    bf16x8 aF = *reinterpret_cast<bf16x8*>(&sA[sl * 40 + g * 8]);
    #pragma unroll
    for (int nt = 0; nt < 4; ++nt) {
      bf16x8 bF = *reinterpret_cast<bf16x8*>(&Xdr[(nt * 16 + sl) * 40 + g * 8]);
      C[nt] = __builtin_amdgcn_mfma_f32_16x16x32_bf16(aF, bF, C[nt], 0, 0, 0);
    }
  }

  // epilogue: D[m=s][n=d]: lane holds d = nt*16+sl, s = 4*g+reg (valid g<2)
  if (g < 2) {
    #pragma unroll
    for (int nt = 0; nt < 4; ++nt)
      #pragma unroll
      for (int r = 0; r < 4; ++r)
        lU[(w * NSLOT + 4 * g + r) * D + nt * 16 + sl] = C[nt][r];
  }
  #pragma unroll
  for (int r = 0; r < 4; ++r) {
    #pragma unroll
    for (int m = 1; m < 16; m <<= 1) Sa[r] += __shfl_xor(Sa[r], m);
  }
  if (g < 2 && sl == 0) {
    #pragma unroll
    for (int r = 0; r < 4; ++r) lS[w * NSLOT + 4 * g + r] = Sa[r];
  }
  __syncthreads();

  for (int cell = tid; cell < NSLOT * D; cell += 256) {
    int s = cell >> 6, d = cell & 63;
    Up[((size_t)(b * NSLOT + s) * NP + rb) * D + d] =
        lU[(0 * NSLOT + s) * D + d] + lU[(1 * NSLOT + s) * D + d] +
        lU[(2 * NSLOT + s) * D + d] + lU[(3 * NSLOT + s) * D + d];
  }
  if (tid < NSLOT)
    Sp[(b * NSLOT + tid) * NP + rb] =
        lS[0 * NSLOT + tid] + lS[1 * NSLOT + tid] +
        lS[2 * NSLOT + tid] + lS[3 * NSLOT + tid];
}

// ---------------------------------------------------------------------------
// prep work (4 blocks of 128 thr, appended to the mode-0 kb launch)
// ---------------------------------------------------------------------------
__device__ void prep_block(int pb,
                           const float* __restrict__ Wq, const float* __restrict__ bq,
                           const float* __restrict__ Wk, const float* __restrict__ bk,
                           const float* __restrict__ Wv, const float* __restrict__ bv,
                           const float* __restrict__ Wih, const float* __restrict__ bih,
                           float* __restrict__ Mt, float* __restrict__ ct,
                           float* __restrict__ u, float* __restrict__ c0,
                           float* __restrict__ G, float* __restrict__ bias_i) {
  const int t = threadIdx.x;  // 0..127
  float acc[32];
  #pragma unroll
  for (int j = 0; j < 32; ++j) acc[j] = 0.f;
  if (pb == 0) {
    const int row = t >> 1;
    const int cb  = (t & 1) * 32;
    for (int f = 0; f < 64; ++f) {
      float wkf = Wk[f * 64 + row];
      const float4* wq4 = reinterpret_cast<const float4*>(Wq + f * 64 + cb);
      #pragma unroll
      for (int j4 = 0; j4 < 8; ++j4) {
        float4 wq = wq4[j4];
        acc[4 * j4 + 0] = fmaf(wkf, wq.x, acc[4 * j4 + 0]);
        acc[4 * j4 + 1] = fmaf(wkf, wq.y, acc[4 * j4 + 1]);
        acc[4 * j4 + 2] = fmaf(wkf, wq.z, acc[4 * j4 + 2]);
        acc[4 * j4 + 3] = fmaf(wkf, wq.w, acc[4 * j4 + 3]);
      }
    }
    #pragma unroll
    for (int j = 0; j < 32; ++j) Mt[row * 64 + cb + j] = acc[j];
    if (t < 64) {
      float a = 0.f, bsum = 0.f;
      for (int f = 0; f < 64; ++f) {
        a    = fmaf(bq[f], Wk[f * 64 + t], a);
        bsum = fmaf(bk[f], Wq[f * 64 + t], bsum);
      }
      ct[t] = a;
      u[t]  = bsum;
    }
    if (t == 0) {
      float a = 0.f;
      for (int f = 0; f < 64; ++f) a = fmaf(bk[f], bq[f], a);
      c0[0] = a;
    }
  } else {
    const int r0  = (pb - 1) * 64;
    const int row = r0 + (t >> 1);
    const int cb  = (t & 1) * 32;
    for (int f = 0; f < 64; ++f) {
      float wih = Wih[row * 64 + f];
      const float4* wv4 = reinterpret_cast<const float4*>(Wv + f * 64 + cb);
      #pragma unroll
      for (int j4 = 0; j4 < 8; ++j4) {
        float4 wv = wv4[j4];
        acc[4 * j4 + 0] = fmaf(wih, wv.x, acc[4 * j4 + 0]);
        acc[4 * j4 + 1] = fmaf(wih, wv.y, acc[4 * j4 + 1]);
        acc[4 * j4 + 2] = fmaf(wih, wv.z, acc[4 * j4 + 2]);
        acc[4 * j4 + 3] = fmaf(wih, wv.w, acc[4 * j4 + 3]);
      }
    }
    #pragma unroll
    for (int j = 0; j < 32; ++j) G[row * 64 + cb + j] = acc[j];
    if (t < 64) {
      int rr = r0 + t;
      float a = bih[rr];
      for (int f = 0; f < 64; ++f) a = fmaf(Wih[rr * 64 + f], bv[f], a);
      bias_i[rr] = a;
    }
  }
}

// ---------------------------------------------------------------------------
// KB: per-(batch,slot), 128 threads = 2 waves (unchanged from r10).
// ---------------------------------------------------------------------------
__global__ __launch_bounds__(128, 1)
void kb_kernel(int mode, int last,
               const float* __restrict__ noise, const float* __restrict__ mu,
               const float* __restrict__ sigma,
               const float* __restrict__ Wq, const float* __restrict__ bq,
               const float* __restrict__ Wk, const float* __restrict__ bk,
               const float* __restrict__ Wv, const float* __restrict__ bv,
               const float* __restrict__ Wih, const float* __restrict__ bih,
               float* __restrict__ G, float* __restrict__ bias_i,
               const float* __restrict__ Whh, const float* __restrict__ bhh,
               const float* __restrict__ W1, const float* __restrict__ b1,
               const float* __restrict__ W2, const float* __restrict__ b2,
               float* __restrict__ Mt, float* __restrict__ ct,
               float* __restrict__ u, float* __restrict__ c0,
               float* __restrict__ slots, float* __restrict__ qtil,
               float* __restrict__ cvec, const float* __restrict__ Up,
               const float* __restrict__ Sp, float* __restrict__ out) {
  if (blockIdx.x >= NB * NSLOT) {  // prep blocks (mode-0 launch only)
    prep_block(blockIdx.x - NB * NSLOT, Wq, bq, Wk, bk, Wv, bv, Wih, bih,
               Mt, ct, u, c0, G, bias_i);
    return;
  }

  const int blk = blockIdx.x;
  const int b   = blk >> 3;
  const int s   = blk & 7;
  const int wv  = threadIdx.x >> 6;
  const int d   = threadIdx.x & 63;
  const int idx = (b * NSLOT + s) * D + d;

  __shared__ float bufA[64];
  __shared__ float bufQ[64];
  __shared__ float gi[192];
  __shared__ float gh[192];
  __shared__ float bufH[128];

  if (mode == 0) {
    if (wv == 0) {
      float h = mu[d] + sigma[d] * noise[idx];
      slots[idx] = h;
      float m  = wredsum(h) * (1.f / 64.f);
      float hc = h - m;
      float v  = wredsum(hc * hc) * (1.f / 64.f);
      float ln = hc * rsqrtf(v + EPS);
      bufA[d] = ln;
      matvec_pre<64>(Wq, bufA, gi, d);
      float qv = gi[d] + bq[d];
      bufQ[d] = qv;
      float qt0 = 0.f, qt1 = 0.f, qt2 = 0.f, qt3 = 0.f;
      #pragma unroll
      for (int e = 0; e < 64; e += 4) {
        const float4 qb = *reinterpret_cast<const float4*>(bufQ + e);
        qt0 = fmaf(Wk[(e + 0) * D + d], qb.x, qt0);
        qt1 = fmaf(Wk[(e + 1) * D + d], qb.y, qt1);
        qt2 = fmaf(Wk[(e + 2) * D + d], qb.z, qt2);
        qt3 = fmaf(Wk[(e + 3) * D + d], qb.w, qt3);
      }
      qtil[idx] = ((qt0 + qt1) + (qt2 + qt3)) * SCK;
      float ca = wredsum(bk[d] * qv) * SCK;
      if (d == 0) cvec[b * NSLOT + s] = ca;
    }
    return;
  }

  // ---- mode 1 ----
  float h = 0.f, sl = 0.f;
  if (wv == 0) {
    const float* up = Up + (size_t)(b * NSLOT + s) * NP * D + d;
    float acc = 0.f;
    #pragma unroll
    for (int p = 0; p < NP; ++p) acc += up[p * D];
    const float* sp = Sp + (b * NSLOT + s) * NP;
    float ss = 0.f;
    #pragma unroll
    for (int p = 0; p < NP; ++p) ss += sp[p];
    bufA[d] = acc / ss;
    h = slots[idx];
    bufH[d] = h;
  }
  __syncthreads();
  if (wv == 0) matvec_pre<192>(G,   bufA, gi, d);
  else         matvec_pre<192>(Whh, bufH, gh, d);
  __syncthreads();
  if (wv == 0) {
    float r  = 1.f / (1.f + expf(-(gi[d]        + bias_i[d]        + gh[d]        + bhh[d])));
    float z  = 1.f / (1.f + expf(-(gi[64 + d]   + bias_i[64 + d]   + gh[64 + d]   + bhh[64 + d])));
    float nn = tanhf(gi[128 + d] + bias_i[128 + d] + r * (gh[128 + d] + bhh[128 + d]));
    h = (1.f - z) * nn + z * h;
    float m  = wredsum(h) * (1.f / 64.f);
    float hc = h - m;
    float v  = wredsum(hc * hc) * (1.f / 64.f);
    sl = hc * rsqrtf(v + EPS);
    bufA[d] = sl;
  }
  __syncthreads();
  matvec_pre<64>(W1 + wv * 64 * 64, bufA, gi + wv * 64, d);
  __syncthreads();
  bufH[threadIdx.x] = fmaxf(gi[threadIdx.x] + b1[threadIdx.x], 0.f);
  __syncthreads();
  matvec_pre_c128<32>(W2 + wv * 32 * 128, bufH, gh + wv * 32, d);
  __syncthreads();
  if (wv == 0) {
    h = sl + gh[d] + b2[d];
    slots[idx] = h;
    if (last) out[idx] = h;
  }

  if (!last) {
    if (wv == 0) {
      float m  = wredsum(h) * (1.f / 64.f);
      float hc = h - m;
      float v  = wredsum(hc * hc) * (1.f / 64.f);
      float ln = hc * rsqrtf(v + EPS);
      bufA[d] = ln;
    }
    __syncthreads();
    matvec_pre<32>(Mt + wv * 32 * 64, bufA, gi + wv * 32, d);
    __syncthreads();
    if (wv == 0) {
      qtil[idx] = SCK * (gi[d] + ct[d]);
      float ca = (wredsum(u[d] * bufA[d]) + c0[0]) * SCK;
      if (d == 0) cvec[b * NSLOT + s] = ca;
    }
  }
}

// ---------------------------------------------------------------------------
extern "C" void kernel_launch(void* const* d_in, const int* in_sizes, int n_in,
                              void* d_out, int out_size, void* d_ws, size_t ws_size,
                              hipStream_t stream) {
  (void)in_sizes; (void)n_in; (void)out_size;
  const float* x     = (const float*)d_in[0];
  const float* noise = (const float*)d_in[1];
  const float* Wq    = (const float*)d_in[2];
  const float* bq    = (const float*)d_in[3];
  const float* Wk    = (const float*)d_in[4];
  const float* bk    = (const float*)d_in[5];
  const float* Wv    = (const float*)d_in[6];
  const float* bv    = (const float*)d_in[7];
  const float* Wih   = (const float*)d_in[8];
  const float* Whh   = (const float*)d_in[9];
  const float* bih   = (const float*)d_in[10];
  const float* bhh   = (const float*)d_in[11];
  const float* W1    = (const float*)d_in[12];
  const float* b1    = (const float*)d_in[13];
  const float* W2    = (const float*)d_in[14];
  const float* b2    = (const float*)d_in[15];
  const float* mu    = (const float*)d_in[16];
  const float* sigma = (const float*)d_in[17];

  float* ws     = (float*)d_ws;
  float* slots  = ws;           // 32768
  float* qtil   = ws + 32768;   // 32768
  float* cvec   = ws + 65536;   // 512
  float* Mt     = ws + 66048;   // 4096
  float* ct     = ws + 70144;   // 64
  float* uvec   = ws + 70208;   // 64
  float* c0     = ws + 70272;   // 16 (padded)
  float* G      = ws + 70288;   // 12288
  float* bias_i = ws + 82576;   // 192
  float* Up     = ws + 82768;   // 524288
  float* Sp     = ws + 607056;  // 8192 -> end 615248
  ushortt* xnb  = (ushortt*)(ws + 615296);  // 16.78M shorts = 33.5 MB
  float* out    = (float*)d_out;

  const bool use_xnb = ws_size >= (size_t)(615296 + 8388608) * sizeof(float);

  const int SM1 = 52352;  // Xdr+sA+lU+lS+Xrd
  const int SM2 = 33920;  // Xdr+sA+lU+lS

  auto launch_kb = [&](int mode, int last, int nblk) {
    kb_kernel<<<nblk, 128, 0, stream>>>(mode, last, noise, mu, sigma,
                                        Wq, bq, Wk, bk, Wv, bv, Wih, bih,
                                        G, bias_i, Whh, bhh, W1, b1, W2, b2,
                                        Mt, ct, uvec, c0,
                                        slots, qtil, cvec, Up, Sp, out);
  };

  launch_kb(0, 0, NB * NSLOT + 4);  // init + q~ (unfolded) + prep blocks
  for (int it = 1; it <= 3; ++it) {
    if (!use_xnb) {
      kam_kernel<1><<<NB * NP, 256, SM1, stream>>>(x, xnb, 0, qtil, cvec, Up, Sp);
    } else if (it == 1) {
      kam_kernel<1><<<NB * NP, 256, SM1, stream>>>(x, xnb, 1, qtil, cvec, Up, Sp);
    } else {
      kam_kernel<2><<<NB * NP, 256, SM2, stream>>>(x, xnb, 0, qtil, cvec, Up, Sp);
    }
    launch_kb(1, it == 3 ? 1 : 0, NB * NSLOT);
  }
}